// Round 1
// baseline (2704.376 us; speedup 1.0000x reference)
//
#include <hip/hip_runtime.h>
#include <hip/hip_bf16.h>

typedef __bf16 bf16_t;
typedef __attribute__((ext_vector_type(4))) float f32x4;
typedef __attribute__((ext_vector_type(8))) bf16_t bf16x8;
typedef __attribute__((ext_vector_type(4))) bf16_t bf16x4;

#define D_MODEL 1536
#define NH 12
#define DHD 128
#define S_TXT 512
#define S_TOT 1536
#define FF_DIM 6144

// Load an 8-element bf16 MFMA fragment: k-halves at p[0..3] and p[16..19].
__device__ inline bf16x8 ld_frag(const bf16_t* p) {
    bf16x4 a = *(const bf16x4*)p;
    bf16x4 b = *(const bf16x4*)(p + 16);
    bf16x8 r;
    r[0]=a[0]; r[1]=a[1]; r[2]=a[2]; r[3]=a[3];
    r[4]=b[0]; r[5]=b[1]; r[6]=b[2]; r[7]=b[3];
    return r;
}

// ---------------------------------------------------------------------------
// adaLN: emb = silu(temb) @ W + b  for img and txt.  grid 72 x 256.
// ---------------------------------------------------------------------------
__global__ __launch_bounds__(256)
void adaln_gemv(const float* __restrict__ temb,
                const float* __restrict__ w_img, const float* __restrict__ b_img,
                const float* __restrict__ w_txt, const float* __restrict__ b_txt,
                float* __restrict__ emb_img, float* __restrict__ emb_txt) {
    __shared__ float t[D_MODEL];
    int tid = threadIdx.x;
#pragma unroll
    for (int i = 0; i < 6; ++i) {
        int k = tid + 256 * i;
        float x = temb[k];
        t[k] = x / (1.0f + __expf(-x));
    }
    __syncthreads();
    bool img = blockIdx.x < 36;
    int n = (img ? blockIdx.x : blockIdx.x - 36) * 256 + tid;
    const float* W = img ? w_img : w_txt;
    float acc = img ? b_img[n] : b_txt[n];
    for (int k = 0; k < D_MODEL; k += 4) {
        acc += t[k]     * W[(size_t)k * 9216 + n];
        acc += t[k + 1] * W[(size_t)(k + 1) * 9216 + n];
        acc += t[k + 2] * W[(size_t)(k + 2) * 9216 + n];
        acc += t[k + 3] * W[(size_t)(k + 3) * 9216 + n];
    }
    (img ? emb_img : emb_txt)[n] = acc;
}

// ---------------------------------------------------------------------------
// LayerNorm + modulate. Rows 0..511 from src_txt (emb_t), 512..1535 src_img.
// out = ln(x)*(1+emb[sc_c*D+d]) + emb[sh_c*D+d]
// ---------------------------------------------------------------------------
__global__ __launch_bounds__(256)
void ln_mod(const float* __restrict__ src_txt, const float* __restrict__ src_img,
            const float* __restrict__ emb_t, const float* __restrict__ emb_i,
            int sh_c, int sc_c, float* __restrict__ out) {
    int row = blockIdx.x;
    bool txt = row < S_TXT;
    const float* src = txt ? src_txt + (size_t)row * D_MODEL
                           : src_img + (size_t)(row - S_TXT) * D_MODEL;
    const float* emb = txt ? emb_t : emb_i;
    int tid = threadIdx.x;
    float2 v[3];
    float s = 0.f, sq = 0.f;
#pragma unroll
    for (int i = 0; i < 3; ++i) {
        v[i] = *(const float2*)(src + tid * 2 + 512 * i);
        s  += v[i].x + v[i].y;
        sq += v[i].x * v[i].x + v[i].y * v[i].y;
    }
#pragma unroll
    for (int off = 32; off > 0; off >>= 1) {
        s  += __shfl_down(s, off);
        sq += __shfl_down(sq, off);
    }
    __shared__ float red[8];
    int wave = tid >> 6, lane = tid & 63;
    if (lane == 0) { red[wave] = s; red[4 + wave] = sq; }
    __syncthreads();
    float ts = red[0] + red[1] + red[2] + red[3];
    float tq = red[4] + red[5] + red[6] + red[7];
    float mean = ts * (1.0f / D_MODEL);
    float var  = tq * (1.0f / D_MODEL) - mean * mean;
    float rstd = rsqrtf(var + 1e-6f);
    float* op = out + (size_t)row * D_MODEL;
#pragma unroll
    for (int i = 0; i < 3; ++i) {
        int c0 = tid * 2 + 512 * i;
        float2 r;
        r.x = (v[i].x - mean) * rstd * (1.0f + emb[sc_c * D_MODEL + c0])     + emb[sh_c * D_MODEL + c0];
        r.y = (v[i].y - mean) * rstd * (1.0f + emb[sc_c * D_MODEL + c0 + 1]) + emb[sh_c * D_MODEL + c0 + 1];
        *(float2*)(op + c0) = r;
    }
}

// ---------------------------------------------------------------------------
// bf16 MFMA GEMM: out(MxN) = A(MxK,f32) @ W(KxN,f32) + bias, epilogue variants.
// 128x128 tile, BK=64, 256 threads (4 waves 2x2), fp32->bf16 staged in LDS.
// EPI: 0=bias  1=bias+gelu(tanh)  2=resid + gate*(bias+acc)
// ---------------------------------------------------------------------------
template <int EPI>
__global__ __launch_bounds__(256, 2)
void gemm_k(const float* __restrict__ A, int lda,
            const float* __restrict__ W, int ldw,
            const float* __restrict__ bias,
            const float* __restrict__ resid, int ldr,
            const float* __restrict__ gate,
            float* __restrict__ out, int ldo, int K) {
    __shared__ bf16_t As[128][68];   // [m][k], pad+4 -> conflict-free b64 frag reads
    __shared__ bf16_t Bs[128][68];   // [n][k] (transposed at stage time)
    const int tid = threadIdx.x;
    const int bm = blockIdx.y * 128;
    const int bn = blockIdx.x * 128;
    const int wave = tid >> 6, lane = tid & 63;
    const int wr = (wave >> 1) * 64, wc = (wave & 1) * 64;
    const int lr = lane & 15, lg = lane >> 4;

    f32x4 acc[4][4] = {};

    for (int k0 = 0; k0 < K; k0 += 64) {
        // stage A: 128x64 f32 -> bf16, float4 loads (coalesced)
#pragma unroll
        for (int j = 0; j < 8; ++j) {
            int linear = tid + 256 * j;
            int r = linear >> 4, c4 = linear & 15;
            const float4 v = *(const float4*)(A + (size_t)(bm + r) * lda + k0 + c4 * 4);
            bf16x4 pk;
            pk[0] = (bf16_t)v.x; pk[1] = (bf16_t)v.y; pk[2] = (bf16_t)v.z; pk[3] = (bf16_t)v.w;
            *(bf16x4*)&As[r][c4 * 4] = pk;
        }
        // stage B transposed: thread reads 4 rows (coalesced in n), writes [n][k] b64
#pragma unroll
        for (int j = 0; j < 8; ++j) {
            int linear = tid + 256 * j;
            int n = linear & 127, kq = linear >> 7;
            const float* wp = W + (size_t)(k0 + kq * 4) * ldw + bn + n;
            bf16x4 pk;
            pk[0] = (bf16_t)wp[0];
            pk[1] = (bf16_t)wp[ldw];
            pk[2] = (bf16_t)wp[2 * ldw];
            pk[3] = (bf16_t)wp[3 * ldw];
            *(bf16x4*)&Bs[n][kq * 4] = pk;
        }
        __syncthreads();
#pragma unroll
        for (int kk = 0; kk < 64; kk += 32) {
            bf16x8 af[4], bfm[4];
#pragma unroll
            for (int m = 0; m < 4; ++m) af[m] = ld_frag(&As[wr + m * 16 + lr][kk + lg * 4]);
#pragma unroll
            for (int n = 0; n < 4; ++n) bfm[n] = ld_frag(&Bs[wc + n * 16 + lr][kk + lg * 4]);
#pragma unroll
            for (int m = 0; m < 4; ++m)
#pragma unroll
                for (int n = 0; n < 4; ++n)
                    acc[m][n] = __builtin_amdgcn_mfma_f32_16x16x32_bf16(af[m], bfm[n], acc[m][n], 0, 0, 0);
        }
        __syncthreads();
    }
    // epilogue: D row=(lane>>4)*4+r, col=lane&15  (HW-verified mapping)
#pragma unroll
    for (int m = 0; m < 4; ++m) {
#pragma unroll
        for (int r = 0; r < 4; ++r) {
            int grow = bm + wr + m * 16 + lg * 4 + r;
#pragma unroll
            for (int n = 0; n < 4; ++n) {
                int gcol = bn + wc + n * 16 + lr;
                float v = acc[m][n][r] + bias[gcol];
                if constexpr (EPI == 1) {
                    float x = v;
                    float th = tanhf(0.7978845608028654f * (x + 0.044715f * x * x * x));
                    v = 0.5f * x * (1.0f + th);
                } else if constexpr (EPI == 2) {
                    v = resid[(size_t)grow * ldr + gcol] + gate[gcol] * v;
                }
                out[(size_t)grow * ldo + gcol] = v;
            }
        }
    }
}

// ---------------------------------------------------------------------------
// QKV epilogue: RMS-norm(q,k) + RoPE + fold 1/sqrt(DH) into q; bf16 out.
// grid (12, 1536), block 128 (one (h,s) row; thread = dh).
// ---------------------------------------------------------------------------
__global__ __launch_bounds__(128)
void qkv_epi(const float* __restrict__ qkv, const float* __restrict__ rope,
             const float* __restrict__ qn_i, const float* __restrict__ kn_i,
             const float* __restrict__ qn_t, const float* __restrict__ kn_t,
             bf16_t* __restrict__ qb, bf16_t* __restrict__ kb) {
    int h = blockIdx.x, s = blockIdx.y, dh = threadIdx.x;
    bool txt = s < S_TXT;
    const float* qn = txt ? qn_t : qn_i;
    const float* kn = txt ? kn_t : kn_i;
    const float* base = qkv + (size_t)s * 4608 + h * DHD + dh;
    float q = base[0];
    float k = base[D_MODEL];
    float qs = q * q, ks = k * k;
#pragma unroll
    for (int off = 32; off > 0; off >>= 1) {
        qs += __shfl_down(qs, off);
        ks += __shfl_down(ks, off);
    }
    __shared__ float red[4];
    if ((threadIdx.x & 63) == 0) {
        red[(threadIdx.x >> 6) * 2]     = qs;
        red[(threadIdx.x >> 6) * 2 + 1] = ks;
    }
    __syncthreads();
    float qr = rsqrtf((red[0] + red[2]) * (1.0f / DHD) + 1e-6f);
    float kr = rsqrtf((red[1] + red[3]) * (1.0f / DHD) + 1e-6f);
    q = q * qr * qn[dh];
    k = k * kr * kn[dh];
    int i = dh & 1, d = dh >> 1;
    const float* rp = rope + ((size_t)s * 64 + d) * 4 + i * 2;
    float r0 = rp[0], r1 = rp[1];
    float qo = __shfl_xor(q, 1), ko = __shfl_xor(k, 1);
    float q0 = i ? qo : q, q1 = i ? q : qo;
    float k0 = i ? ko : k, k1 = i ? k : ko;
    float qq = r0 * q0 + r1 * q1;
    float kk = r0 * k0 + r1 * k1;
    size_t idx = ((size_t)h * S_TOT + s) * DHD + dh;
    qb[idx] = (bf16_t)(qq * 0.08838834764831845f);  // 1/sqrt(128)
    kb[idx] = (bf16_t)kk;
}

// ---------------------------------------------------------------------------
// V transpose: per-head vT[DH][S] bf16 so PV B-fragments read contiguous.
// grid (12, 24), block 256.
// ---------------------------------------------------------------------------
__global__ __launch_bounds__(256)
void v_tr(const float* __restrict__ qkv, bf16_t* __restrict__ vt) {
    __shared__ bf16_t tile[64][130];
    int h = blockIdx.x, sb = blockIdx.y * 64;
    int tid = threadIdx.x;
#pragma unroll
    for (int j = 0; j < 32; ++j) {
        int linear = tid + 256 * j;
        int sl = linear >> 7, dh = linear & 127;
        tile[sl][dh] = (bf16_t)qkv[(size_t)(sb + sl) * 4608 + 2 * D_MODEL + h * DHD + dh];
    }
    __syncthreads();
#pragma unroll
    for (int j = 0; j < 32; ++j) {
        int linear = tid + 256 * j;
        int dh = linear >> 6, sl = linear & 63;
        vt[((size_t)h * DHD + dh) * S_TOT + sb + sl] = tile[sl][dh];
    }
}

// ---------------------------------------------------------------------------
// Flash attention: grid (12, 24) = (head, q-block of 64), 4 waves x 16 q-rows.
// Q in regs, K/V from global (L1/L2 resident), P via per-wave LDS bounce.
// Online softmax with shfl_xor row reductions. o is (S, D) fp32.
// ---------------------------------------------------------------------------
__global__ __launch_bounds__(256)
void attn_k(const bf16_t* __restrict__ qb, const bf16_t* __restrict__ kb,
            const bf16_t* __restrict__ vt, float* __restrict__ o) {
    __shared__ bf16_t P[4][16][68];
    int h = blockIdx.x, q0 = blockIdx.y * 64;
    int tid = threadIdx.x, wave = tid >> 6, lane = tid & 63;
    int lr = lane & 15, lg = lane >> 4;
    const bf16_t* Qp = qb + ((size_t)h * S_TOT + q0 + wave * 16 + lr) * DHD;
    bf16x8 qf[4];
#pragma unroll
    for (int kk = 0; kk < 4; ++kk) qf[kk] = ld_frag(Qp + kk * 32 + lg * 4);
    f32x4 of[8] = {};
    float m[4] = {-1e30f, -1e30f, -1e30f, -1e30f};
    float l[4] = {};
    for (int kb0 = 0; kb0 < S_TOT; kb0 += 64) {
        f32x4 sf[4] = {};
#pragma unroll
        for (int n = 0; n < 4; ++n) {
            const bf16_t* Kp = kb + ((size_t)h * S_TOT + kb0 + n * 16 + lr) * DHD;
#pragma unroll
            for (int kk = 0; kk < 4; ++kk) {
                bf16x8 kf = ld_frag(Kp + kk * 32 + lg * 4);
                sf[n] = __builtin_amdgcn_mfma_f32_16x16x32_bf16(qf[kk], kf, sf[n], 0, 0, 0);
            }
        }
        float bm[4], alpha[4], rs[4];
#pragma unroll
        for (int r = 0; r < 4; ++r)
            bm[r] = fmaxf(fmaxf(sf[0][r], sf[1][r]), fmaxf(sf[2][r], sf[3][r]));
#pragma unroll
        for (int mask = 1; mask < 16; mask <<= 1)
#pragma unroll
            for (int r = 0; r < 4; ++r) bm[r] = fmaxf(bm[r], __shfl_xor(bm[r], mask));
#pragma unroll
        for (int r = 0; r < 4; ++r) {
            float mn = fmaxf(m[r], bm[r]);
            alpha[r] = __expf(m[r] - mn);
            m[r] = mn;
            rs[r] = 0.f;
        }
#pragma unroll
        for (int n = 0; n < 4; ++n)
#pragma unroll
            for (int r = 0; r < 4; ++r) {
                float p = __expf(sf[n][r] - m[r]);
                rs[r] += p;
                P[wave][lg * 4 + r][n * 16 + lr] = (bf16_t)p;
            }
#pragma unroll
        for (int mask = 1; mask < 16; mask <<= 1)
#pragma unroll
            for (int r = 0; r < 4; ++r) rs[r] += __shfl_xor(rs[r], mask);
#pragma unroll
        for (int r = 0; r < 4; ++r) l[r] = l[r] * alpha[r] + rs[r];
#pragma unroll
        for (int nf = 0; nf < 8; ++nf)
#pragma unroll
            for (int r = 0; r < 4; ++r) of[nf][r] *= alpha[r];
        __syncthreads();  // P writes -> reads (lgkmcnt drain + ordering)
#pragma unroll
        for (int kk2 = 0; kk2 < 2; ++kk2) {
            bf16x8 pf = ld_frag(&P[wave][lr][kk2 * 32 + lg * 4]);
#pragma unroll
            for (int nf = 0; nf < 8; ++nf) {
                const bf16_t* Vp = vt + ((size_t)h * DHD + nf * 16 + lr) * S_TOT + kb0 + kk2 * 32 + lg * 4;
                bf16x8 vf = ld_frag(Vp);
                of[nf] = __builtin_amdgcn_mfma_f32_16x16x32_bf16(pf, vf, of[nf], 0, 0, 0);
            }
        }
        __syncthreads();  // reads done before next iteration overwrites P
    }
    int orow = q0 + wave * 16 + lg * 4;
#pragma unroll
    for (int r = 0; r < 4; ++r) {
        float inv = 1.0f / l[r];
#pragma unroll
        for (int nf = 0; nf < 8; ++nf)
            o[(size_t)(orow + r) * D_MODEL + h * DHD + nf * 16 + lr] = of[nf][r] * inv;
    }
}

// ---------------------------------------------------------------------------
extern "C" void kernel_launch(void* const* d_in, const int* in_sizes, int n_in,
                              void* d_out, int out_size, void* d_ws, size_t ws_size,
                              hipStream_t stream) {
    const float* hidden  = (const float*)d_in[0];
    const float* encoder = (const float*)d_in[1];
    const float* temb    = (const float*)d_in[2];
    const float* rope    = (const float*)d_in[3];
    const float* adaln_img_w = (const float*)d_in[4];
    const float* adaln_img_b = (const float*)d_in[5];
    const float* adaln_txt_w = (const float*)d_in[6];
    const float* adaln_txt_b = (const float*)d_in[7];
    const float* qkv_img_w = (const float*)d_in[8];
    const float* qkv_img_b = (const float*)d_in[9];
    const float* qkv_txt_w = (const float*)d_in[10];
    const float* qkv_txt_b = (const float*)d_in[11];
    const float* qn_img = (const float*)d_in[12];
    const float* kn_img = (const float*)d_in[13];
    const float* qn_txt = (const float*)d_in[14];
    const float* kn_txt = (const float*)d_in[15];
    const float* out_img_w = (const float*)d_in[16];
    const float* out_img_b = (const float*)d_in[17];
    const float* out_txt_w = (const float*)d_in[18];
    const float* out_txt_b = (const float*)d_in[19];
    const float* mlp_img_w1 = (const float*)d_in[20];
    const float* mlp_img_b1 = (const float*)d_in[21];
    const float* mlp_img_w2 = (const float*)d_in[22];
    const float* mlp_img_b2 = (const float*)d_in[23];
    const float* mlp_txt_w1 = (const float*)d_in[24];
    const float* mlp_txt_b1 = (const float*)d_in[25];
    const float* mlp_txt_w2 = (const float*)d_in[26];
    const float* mlp_txt_b2 = (const float*)d_in[27];
    float* dout = (float*)d_out;
    float* ws = (float*)d_ws;

    // ws layout (floats). Total 15,353,856 floats = 61.4 MB.
    float* emb_i = ws;                    // 9216
    float* emb_t = ws + 9216;             // 9216
    float* n_buf = ws + 18432;            // 1536*1536   (LN out; later aliased by o_buf, then LN2 out)
    float* o_buf = n_buf;                 // alias: o live only between attn and out-proj
    float* qkvb  = ws + 2377728;          // region2: max(1536*4608, 1536*6144) = 9437184
    float* ffb   = qkvb;                  // alias: ff lives after qkv is consumed
    bf16_t* qb = (bf16_t*)(ws + 11814912);  // 12*1536*128 bf16
    bf16_t* kb = (bf16_t*)(ws + 12994560);
    bf16_t* vt = (bf16_t*)(ws + 14174208);

    // 1. adaLN embeddings
    adaln_gemv<<<72, 256, 0, stream>>>(temb, adaln_img_w, adaln_img_b,
                                       adaln_txt_w, adaln_txt_b, emb_i, emb_t);
    // 2. LN1 + modulate (chunks sh=0, sc=1)
    ln_mod<<<S_TOT, 256, 0, stream>>>(encoder, hidden, emb_t, emb_i, 0, 1, n_buf);
    // 3. QKV GEMMs
    gemm_k<0><<<dim3(36, 4), 256, 0, stream>>>(n_buf, D_MODEL, qkv_txt_w, 4608, qkv_txt_b,
                                               nullptr, 0, nullptr, qkvb, 4608, D_MODEL);
    gemm_k<0><<<dim3(36, 8), 256, 0, stream>>>(n_buf + (size_t)512 * D_MODEL, D_MODEL, qkv_img_w, 4608,
                                               qkv_img_b, nullptr, 0, nullptr,
                                               qkvb + (size_t)512 * 4608, 4608, D_MODEL);
    // 4. RMS + RoPE + scale -> bf16 q,k
    qkv_epi<<<dim3(12, 1536), 128, 0, stream>>>(qkvb, rope, qn_img, kn_img, qn_txt, kn_txt, qb, kb);
    // 5. V transpose -> bf16 vT[h][dh][s]
    v_tr<<<dim3(12, 24), 256, 0, stream>>>(qkvb, vt);
    // 6. attention -> o (S, D) fp32
    attn_k<<<dim3(12, 24), 256, 0, stream>>>(qb, kb, vt, o_buf);
    // 7. out-proj + gate + residual -> d_out (rows 0..511 txt, 512..1535 img)
    gemm_k<2><<<dim3(12, 4), 256, 0, stream>>>(o_buf, D_MODEL, out_txt_w, D_MODEL, out_txt_b,
                                               encoder, D_MODEL, emb_t + 2 * D_MODEL,
                                               dout, D_MODEL, D_MODEL);
    gemm_k<2><<<dim3(12, 8), 256, 0, stream>>>(o_buf + (size_t)512 * D_MODEL, D_MODEL, out_img_w, D_MODEL,
                                               out_img_b, hidden, D_MODEL, emb_i + 2 * D_MODEL,
                                               dout + (size_t)512 * D_MODEL, D_MODEL, D_MODEL);
    // 8. LN2 + modulate (chunks shm=3, scm=4)
    ln_mod<<<S_TOT, 256, 0, stream>>>(dout, dout + (size_t)512 * D_MODEL, emb_t, emb_i, 3, 4, n_buf);
    // 9. MLP up + gelu
    gemm_k<1><<<dim3(48, 4), 256, 0, stream>>>(n_buf, D_MODEL, mlp_txt_w1, FF_DIM, mlp_txt_b1,
                                               nullptr, 0, nullptr, ffb, FF_DIM, D_MODEL);
    gemm_k<1><<<dim3(48, 8), 256, 0, stream>>>(n_buf + (size_t)512 * D_MODEL, D_MODEL, mlp_img_w1, FF_DIM,
                                               mlp_img_b1, nullptr, 0, nullptr,
                                               ffb + (size_t)512 * FF_DIM, FF_DIM, D_MODEL);
    // 10. MLP down + gate + residual (in-place on d_out)
    gemm_k<2><<<dim3(12, 4), 256, 0, stream>>>(ffb, FF_DIM, mlp_txt_w2, D_MODEL, mlp_txt_b2,
                                               dout, D_MODEL, emb_t + 5 * D_MODEL,
                                               dout, D_MODEL, FF_DIM);
    gemm_k<2><<<dim3(12, 8), 256, 0, stream>>>(ffb + (size_t)512 * FF_DIM, FF_DIM, mlp_img_w2, D_MODEL,
                                               mlp_img_b2, dout + (size_t)512 * D_MODEL, D_MODEL,
                                               emb_i + 5 * D_MODEL,
                                               dout + (size_t)512 * D_MODEL, D_MODEL, FF_DIM);
    (void)in_sizes; (void)n_in; (void)out_size; (void)ws_size;
}

// Round 2
// 1416.668 us; speedup vs baseline: 1.9090x; 1.9090x over previous
//
#include <hip/hip_runtime.h>
#include <hip/hip_bf16.h>

typedef __bf16 bf16_t;
typedef __attribute__((ext_vector_type(4))) float f32x4;
typedef __attribute__((ext_vector_type(8))) bf16_t bf16x8;
typedef __attribute__((ext_vector_type(4))) bf16_t bf16x4;
typedef __attribute__((ext_vector_type(2))) bf16_t bf16x2;

#define D_MODEL 1536
#define NH 12
#define DHD 128
#define S_TXT 512
#define S_TOT 1536
#define FF_DIM 6144

// Load an 8-element bf16 MFMA fragment: k-halves at p[0..3] and p[16..19].
__device__ inline bf16x8 ld_frag(const bf16_t* p) {
    bf16x4 a = *(const bf16x4*)p;
    bf16x4 b = *(const bf16x4*)(p + 16);
    bf16x8 r;
    r[0]=a[0]; r[1]=a[1]; r[2]=a[2]; r[3]=a[3];
    r[4]=b[0]; r[5]=b[1]; r[6]=b[2]; r[7]=b[3];
    return r;
}

// async global->LDS, 16 B per lane. LDS dest must be wave-uniform base (+lane*16 by HW).
__device__ inline void gload16(const void* g, void* l) {
    __builtin_amdgcn_global_load_lds((const __attribute__((address_space(1))) unsigned int*)g,
                                     (__attribute__((address_space(3))) unsigned int*)l, 16, 0, 0);
}

// ---------------------------------------------------------------------------
// adaLN stage 1: partial dot products, K split 8 ways. grid (72,8) block 256.
// part[kc][n_g], n_g: 0..9215 img, 9216..18431 txt.
// ---------------------------------------------------------------------------
__global__ __launch_bounds__(256)
void adaln_p(const float* __restrict__ temb,
             const float* __restrict__ w_img, const float* __restrict__ w_txt,
             float* __restrict__ part) {
    __shared__ float t[192];
    int tid = threadIdx.x;
    int k0 = blockIdx.y * 192;
    if (tid < 192) {
        float x = temb[k0 + tid];
        t[tid] = x / (1.0f + __expf(-x));
    }
    __syncthreads();
    int n_g = blockIdx.x * 256 + tid;
    bool img = n_g < 9216;
    const float* W = img ? w_img : w_txt;
    int n = img ? n_g : n_g - 9216;
    float acc = 0.f;
    for (int kk = 0; kk < 192; kk += 4) {
        acc += t[kk]     * W[(size_t)(k0 + kk) * 9216 + n];
        acc += t[kk + 1] * W[(size_t)(k0 + kk + 1) * 9216 + n];
        acc += t[kk + 2] * W[(size_t)(k0 + kk + 2) * 9216 + n];
        acc += t[kk + 3] * W[(size_t)(k0 + kk + 3) * 9216 + n];
    }
    part[(size_t)blockIdx.y * 18432 + n_g] = acc;
}

// adaLN stage 2: reduce + bias. grid 72 x 256.
__global__ __launch_bounds__(256)
void adaln_r(const float* __restrict__ part,
             const float* __restrict__ b_img, const float* __restrict__ b_txt,
             float* __restrict__ emb_img, float* __restrict__ emb_txt) {
    int n_g = blockIdx.x * 256 + threadIdx.x;
    float a = 0.f;
#pragma unroll
    for (int kc = 0; kc < 8; ++kc) a += part[(size_t)kc * 18432 + n_g];
    if (n_g < 9216) emb_img[n_g] = a + b_img[n_g];
    else            emb_txt[n_g - 9216] = a + b_txt[n_g - 9216];
}

// ---------------------------------------------------------------------------
// LayerNorm + modulate -> bf16. Rows 0..511 txt, 512..1535 img.
// ---------------------------------------------------------------------------
__global__ __launch_bounds__(256)
void ln_mod(const float* __restrict__ src_txt, const float* __restrict__ src_img,
            const float* __restrict__ emb_t, const float* __restrict__ emb_i,
            int sh_c, int sc_c, bf16_t* __restrict__ out) {
    int row = blockIdx.x;
    bool txt = row < S_TXT;
    const float* src = txt ? src_txt + (size_t)row * D_MODEL
                           : src_img + (size_t)(row - S_TXT) * D_MODEL;
    const float* emb = txt ? emb_t : emb_i;
    int tid = threadIdx.x;
    float2 v[3];
    float s = 0.f, sq = 0.f;
#pragma unroll
    for (int i = 0; i < 3; ++i) {
        v[i] = *(const float2*)(src + tid * 2 + 512 * i);
        s  += v[i].x + v[i].y;
        sq += v[i].x * v[i].x + v[i].y * v[i].y;
    }
#pragma unroll
    for (int off = 32; off > 0; off >>= 1) {
        s  += __shfl_down(s, off);
        sq += __shfl_down(sq, off);
    }
    __shared__ float red[8];
    int wave = tid >> 6, lane = tid & 63;
    if (lane == 0) { red[wave] = s; red[4 + wave] = sq; }
    __syncthreads();
    float ts = red[0] + red[1] + red[2] + red[3];
    float tq = red[4] + red[5] + red[6] + red[7];
    float mean = ts * (1.0f / D_MODEL);
    float var  = tq * (1.0f / D_MODEL) - mean * mean;
    float rstd = rsqrtf(var + 1e-6f);
    bf16_t* op = out + (size_t)row * D_MODEL;
#pragma unroll
    for (int i = 0; i < 3; ++i) {
        int c0 = tid * 2 + 512 * i;
        bf16x2 r;
        r[0] = (bf16_t)((v[i].x - mean) * rstd * (1.0f + emb[sc_c * D_MODEL + c0])     + emb[sh_c * D_MODEL + c0]);
        r[1] = (bf16_t)((v[i].y - mean) * rstd * (1.0f + emb[sc_c * D_MODEL + c0 + 1]) + emb[sh_c * D_MODEL + c0 + 1]);
        *(bf16x2*)(op + c0) = r;
    }
}

// ---------------------------------------------------------------------------
// Weight convert+transpose: W f32 [K][N] -> Wt bf16 [N][K]. grid (N/64,K/64,2).
// z=0: txt weight -> dst, z=1: img weight -> dst + N*K.
// ---------------------------------------------------------------------------
template <int K, int N>
__global__ __launch_bounds__(256)
void conv_wt(const float* __restrict__ w_t, const float* __restrict__ w_i,
             bf16_t* __restrict__ dst) {
    __shared__ float tile[64][65];
    const float* src = blockIdx.z ? w_i : w_t;
    bf16_t* d = dst + (size_t)blockIdx.z * N * K;
    int bn = blockIdx.x * 64, bk = blockIdx.y * 64;
    int tid = threadIdx.x;
#pragma unroll
    for (int j = 0; j < 16; ++j) {
        int l = tid + 256 * j;
        int k = l >> 6, n = l & 63;
        tile[k][n] = src[(size_t)(bk + k) * N + bn + n];
    }
    __syncthreads();
#pragma unroll
    for (int j = 0; j < 16; ++j) {
        int l = tid + 256 * j;
        int n = l >> 6, k = l & 63;
        d[(size_t)(bn + n) * K + bk + k] = (bf16_t)tile[k][n];
    }
}

// ---------------------------------------------------------------------------
// bf16 MFMA GEMM (m97 structure): out(MxN) = A(MxK,bf16) @ Wt(NxK,bf16)^T.
// M always 1536: rows <512 use txt params, >=512 img. 128x128 tile, BK=64,
// 256 threads (4 waves 2x2), global_load_lds x16B staging, linear LDS.
// EPI: 0=bias  1=bias+gelu(tanh)  2=resid + gate*(bias+acc)
// ---------------------------------------------------------------------------
template <int EPI, typename OutT>
__global__ __launch_bounds__(256)
void gemm2(const bf16_t* __restrict__ A, int lda,
           const bf16_t* __restrict__ Wt, int wimg_off,
           const float* __restrict__ bias_t, const float* __restrict__ bias_i,
           const float* __restrict__ resid_t, const float* __restrict__ resid_i, int ldr,
           const float* __restrict__ gate_t, const float* __restrict__ gate_i,
           OutT* __restrict__ out, int ldo, int K) {
    __shared__ bf16_t As[128 * 64];
    __shared__ bf16_t Bs[128 * 64];
    const int tid = threadIdx.x;
    const int bm = blockIdx.y * 128, bn = blockIdx.x * 128;
    const bool txt = bm < S_TXT;
    const bf16_t* W = txt ? Wt : Wt + wimg_off;
    const float* bias = txt ? bias_t : bias_i;
    const int wave = tid >> 6, lane = tid & 63;
    const int wr = (wave >> 1) * 64, wc = (wave & 1) * 64;
    const int lr = lane & 15, lg = lane >> 4;

    const int srow = tid >> 3, sc8 = (tid & 7) * 8;   // staging: row advances 32/round
    const bf16_t* Ab = A + (size_t)(bm + srow) * lda + sc8;
    const bf16_t* Wb = W + (size_t)(bn + srow) * K + sc8;
    const int ldsbase = (wave * 64) * 8;              // elems; +256*8 per round

    f32x4 acc[4][4] = {};

    for (int k0 = 0; k0 < K; k0 += 64) {
#pragma unroll
        for (int j = 0; j < 4; ++j) {
            gload16(Ab + (size_t)j * 32 * lda + k0, &As[ldsbase + j * 2048]);
            gload16(Wb + (size_t)j * 32 * K + k0, &Bs[ldsbase + j * 2048]);
        }
        __syncthreads();   // drains vmcnt -> LDS tiles ready
#pragma unroll
        for (int kk = 0; kk < 64; kk += 32) {
            bf16x8 af[4], bfm[4];
#pragma unroll
            for (int m = 0; m < 4; ++m) af[m] = ld_frag(&As[(wr + m * 16 + lr) * 64 + kk + lg * 4]);
#pragma unroll
            for (int n = 0; n < 4; ++n) bfm[n] = ld_frag(&Bs[(wc + n * 16 + lr) * 64 + kk + lg * 4]);
#pragma unroll
            for (int m = 0; m < 4; ++m)
#pragma unroll
                for (int n = 0; n < 4; ++n)
                    acc[m][n] = __builtin_amdgcn_mfma_f32_16x16x32_bf16(af[m], bfm[n], acc[m][n], 0, 0, 0);
        }
        __syncthreads();   // frag reads done before next staging overwrites
    }

    const float* gate  = txt ? gate_t : gate_i;
    const float* resid = txt ? resid_t : resid_i;
    const int rbase = txt ? 0 : S_TXT;
#pragma unroll
    for (int m = 0; m < 4; ++m) {
#pragma unroll
        for (int r = 0; r < 4; ++r) {
            int grow = bm + wr + m * 16 + lg * 4 + r;
#pragma unroll
            for (int n = 0; n < 4; ++n) {
                int gcol = bn + wc + n * 16 + lr;
                float v = acc[m][n][r] + bias[gcol];
                if constexpr (EPI == 1) {
                    float x = v;
                    float th = tanhf(0.7978845608028654f * (x + 0.044715f * x * x * x));
                    v = 0.5f * x * (1.0f + th);
                } else if constexpr (EPI == 2) {
                    v = resid[(size_t)(grow - rbase) * ldr + gcol] + gate[gcol] * v;
                }
                out[(size_t)grow * ldo + gcol] = (OutT)v;
            }
        }
    }
}

// ---------------------------------------------------------------------------
// QKV epilogue: RMS-norm(q,k) + RoPE + fold 1/sqrt(DH) into q; bf16 in/out.
// grid (12, 1536), block 128.
// ---------------------------------------------------------------------------
__global__ __launch_bounds__(128)
void qkv_epi(const bf16_t* __restrict__ qkv, const float* __restrict__ rope,
             const float* __restrict__ qn_i, const float* __restrict__ kn_i,
             const float* __restrict__ qn_t, const float* __restrict__ kn_t,
             bf16_t* __restrict__ qb, bf16_t* __restrict__ kb) {
    int h = blockIdx.x, s = blockIdx.y, dh = threadIdx.x;
    bool txt = s < S_TXT;
    const float* qn = txt ? qn_t : qn_i;
    const float* kn = txt ? kn_t : kn_i;
    const bf16_t* base = qkv + (size_t)s * 4608 + h * DHD + dh;
    float q = (float)base[0];
    float k = (float)base[D_MODEL];
    float qs = q * q, ks = k * k;
#pragma unroll
    for (int off = 32; off > 0; off >>= 1) {
        qs += __shfl_down(qs, off);
        ks += __shfl_down(ks, off);
    }
    __shared__ float red[4];
    if ((threadIdx.x & 63) == 0) {
        red[(threadIdx.x >> 6) * 2]     = qs;
        red[(threadIdx.x >> 6) * 2 + 1] = ks;
    }
    __syncthreads();
    float qr = rsqrtf((red[0] + red[2]) * (1.0f / DHD) + 1e-6f);
    float kr = rsqrtf((red[1] + red[3]) * (1.0f / DHD) + 1e-6f);
    q = q * qr * qn[dh];
    k = k * kr * kn[dh];
    int i = dh & 1, d = dh >> 1;
    const float* rp = rope + ((size_t)s * 64 + d) * 4 + i * 2;
    float r0 = rp[0], r1 = rp[1];
    float qo = __shfl_xor(q, 1), ko = __shfl_xor(k, 1);
    float q0 = i ? qo : q, q1 = i ? q : qo;
    float k0 = i ? ko : k, k1 = i ? k : ko;
    float qq = r0 * q0 + r1 * q1;
    float kk = r0 * k0 + r1 * k1;
    size_t idx = ((size_t)h * S_TOT + s) * DHD + dh;
    qb[idx] = (bf16_t)(qq * 0.08838834764831845f);  // 1/sqrt(128)
    kb[idx] = (bf16_t)kk;
}

// ---------------------------------------------------------------------------
// V transpose: per-head vT[DH][S] bf16. grid (12, 24), block 256.
// ---------------------------------------------------------------------------
__global__ __launch_bounds__(256)
void v_tr(const bf16_t* __restrict__ qkv, bf16_t* __restrict__ vt) {
    __shared__ bf16_t tile[64][130];
    int h = blockIdx.x, sb = blockIdx.y * 64;
    int tid = threadIdx.x;
#pragma unroll
    for (int j = 0; j < 32; ++j) {
        int linear = tid + 256 * j;
        int sl = linear >> 7, dh = linear & 127;
        tile[sl][dh] = qkv[(size_t)(sb + sl) * 4608 + 2 * D_MODEL + h * DHD + dh];
    }
    __syncthreads();
#pragma unroll
    for (int j = 0; j < 32; ++j) {
        int linear = tid + 256 * j;
        int dh = linear >> 6, sl = linear & 63;
        vt[((size_t)h * DHD + dh) * S_TOT + sb + sl] = tile[sl][dh];
    }
}

// ---------------------------------------------------------------------------
// Flash attention: grid (12, 24) = (head, q-block 64), 4 waves x 16 q-rows.
// o written bf16 (S, D).
// ---------------------------------------------------------------------------
__global__ __launch_bounds__(256)
void attn_k(const bf16_t* __restrict__ qb, const bf16_t* __restrict__ kb,
            const bf16_t* __restrict__ vt, bf16_t* __restrict__ o) {
    __shared__ bf16_t P[4][16][68];
    int h = blockIdx.x, q0 = blockIdx.y * 64;
    int tid = threadIdx.x, wave = tid >> 6, lane = tid & 63;
    int lr = lane & 15, lg = lane >> 4;
    const bf16_t* Qp = qb + ((size_t)h * S_TOT + q0 + wave * 16 + lr) * DHD;
    bf16x8 qf[4];
#pragma unroll
    for (int kk = 0; kk < 4; ++kk) qf[kk] = ld_frag(Qp + kk * 32 + lg * 4);
    f32x4 of[8] = {};
    float m[4] = {-1e30f, -1e30f, -1e30f, -1e30f};
    float l[4] = {};
    for (int kb0 = 0; kb0 < S_TOT; kb0 += 64) {
        f32x4 sf[4] = {};
#pragma unroll
        for (int n = 0; n < 4; ++n) {
            const bf16_t* Kp = kb + ((size_t)h * S_TOT + kb0 + n * 16 + lr) * DHD;
#pragma unroll
            for (int kk = 0; kk < 4; ++kk) {
                bf16x8 kf = ld_frag(Kp + kk * 32 + lg * 4);
                sf[n] = __builtin_amdgcn_mfma_f32_16x16x32_bf16(qf[kk], kf, sf[n], 0, 0, 0);
            }
        }
        float bm[4], alpha[4], rs[4];
#pragma unroll
        for (int r = 0; r < 4; ++r)
            bm[r] = fmaxf(fmaxf(sf[0][r], sf[1][r]), fmaxf(sf[2][r], sf[3][r]));
#pragma unroll
        for (int mask = 1; mask < 16; mask <<= 1)
#pragma unroll
            for (int r = 0; r < 4; ++r) bm[r] = fmaxf(bm[r], __shfl_xor(bm[r], mask));
#pragma unroll
        for (int r = 0; r < 4; ++r) {
            float mn = fmaxf(m[r], bm[r]);
            alpha[r] = __expf(m[r] - mn);
            m[r] = mn;
            rs[r] = 0.f;
        }
#pragma unroll
        for (int n = 0; n < 4; ++n)
#pragma unroll
            for (int r = 0; r < 4; ++r) {
                float p = __expf(sf[n][r] - m[r]);
                rs[r] += p;
                P[wave][lg * 4 + r][n * 16 + lr] = (bf16_t)p;
            }
#pragma unroll
        for (int mask = 1; mask < 16; mask <<= 1)
#pragma unroll
            for (int r = 0; r < 4; ++r) rs[r] += __shfl_xor(rs[r], mask);
#pragma unroll
        for (int r = 0; r < 4; ++r) l[r] = l[r] * alpha[r] + rs[r];
#pragma unroll
        for (int nf = 0; nf < 8; ++nf)
#pragma unroll
            for (int r = 0; r < 4; ++r) of[nf][r] *= alpha[r];
        __syncthreads();
#pragma unroll
        for (int kk2 = 0; kk2 < 2; ++kk2) {
            bf16x8 pf = ld_frag(&P[wave][lr][kk2 * 32 + lg * 4]);
#pragma unroll
            for (int nf = 0; nf < 8; ++nf) {
                const bf16_t* Vp = vt + ((size_t)h * DHD + nf * 16 + lr) * S_TOT + kb0 + kk2 * 32 + lg * 4;
                bf16x8 vf = ld_frag(Vp);
                of[nf] = __builtin_amdgcn_mfma_f32_16x16x32_bf16(pf, vf, of[nf], 0, 0, 0);
            }
        }
        __syncthreads();
    }
    int orow = q0 + wave * 16 + lg * 4;
#pragma unroll
    for (int r = 0; r < 4; ++r) {
        float inv = 1.0f / l[r];
#pragma unroll
        for (int nf = 0; nf < 8; ++nf)
            o[(size_t)(orow + r) * D_MODEL + h * DHD + nf * 16 + lr] = (bf16_t)(of[nf][r] * inv);
    }
}

// ---------------------------------------------------------------------------
extern "C" void kernel_launch(void* const* d_in, const int* in_sizes, int n_in,
                              void* d_out, int out_size, void* d_ws, size_t ws_size,
                              hipStream_t stream) {
    const float* hidden  = (const float*)d_in[0];
    const float* encoder = (const float*)d_in[1];
    const float* temb    = (const float*)d_in[2];
    const float* rope    = (const float*)d_in[3];
    const float* adaln_img_w = (const float*)d_in[4];
    const float* adaln_img_b = (const float*)d_in[5];
    const float* adaln_txt_w = (const float*)d_in[6];
    const float* adaln_txt_b = (const float*)d_in[7];
    const float* qkv_img_w = (const float*)d_in[8];
    const float* qkv_img_b = (const float*)d_in[9];
    const float* qkv_txt_w = (const float*)d_in[10];
    const float* qkv_txt_b = (const float*)d_in[11];
    const float* qn_img = (const float*)d_in[12];
    const float* kn_img = (const float*)d_in[13];
    const float* qn_txt = (const float*)d_in[14];
    const float* kn_txt = (const float*)d_in[15];
    const float* out_img_w = (const float*)d_in[16];
    const float* out_img_b = (const float*)d_in[17];
    const float* out_txt_w = (const float*)d_in[18];
    const float* out_txt_b = (const float*)d_in[19];
    const float* mlp_img_w1 = (const float*)d_in[20];
    const float* mlp_img_b1 = (const float*)d_in[21];
    const float* mlp_img_w2 = (const float*)d_in[22];
    const float* mlp_img_b2 = (const float*)d_in[23];
    const float* mlp_txt_w1 = (const float*)d_in[24];
    const float* mlp_txt_b1 = (const float*)d_in[25];
    const float* mlp_txt_w2 = (const float*)d_in[26];
    const float* mlp_txt_b2 = (const float*)d_in[27];
    float* dout = (float*)d_out;
    char* wsb = (char*)d_ws;

    // ws layout (byte offsets), total 70,852,608 B = 67.6 MB.
    float*  emb_i = (float*)(wsb);                    // 9216 f32
    float*  emb_t = (float*)(wsb + 36864);            // 9216 f32
    bf16_t* wreg  = (bf16_t*)(wsb + 73728);           // 18,874,368 bf16 (reused per stage)
    float*  part  = (float*)(wsb + 73728);            // adaln partials overlay (8x18432 f32)
    bf16_t* n1    = (bf16_t*)(wsb + 37822464);        // 1536x1536 bf16 (LN1, later LN2)
    bf16_t* qkvb  = (bf16_t*)(wsb + 42541056);        // 1536x4608 bf16
    bf16_t* obuf  = qkvb;                             // alias (qkvb dead after epi/v_tr)
    bf16_t* ffb   = qkvb + 2359296;                   // 1536x6144 bf16, overlays dead qb/kb
    bf16_t* qb    = (bf16_t*)(wsb + 56696832);        // 12x1536x128 bf16
    bf16_t* kb    = (bf16_t*)(wsb + 61415424);
    bf16_t* vt    = (bf16_t*)(wsb + 66134016);

    // 1. adaLN (K-split + reduce)
    adaln_p<<<dim3(72, 8), 256, 0, stream>>>(temb, adaln_img_w, adaln_txt_w, part);
    adaln_r<<<72, 256, 0, stream>>>(part, adaln_img_b, adaln_txt_b, emb_i, emb_t);
    // 2. LN1 + modulate -> bf16
    ln_mod<<<S_TOT, 256, 0, stream>>>(encoder, hidden, emb_t, emb_i, 0, 1, n1);
    // 3. QKV: convert weights, fused GEMM
    conv_wt<1536, 4608><<<dim3(72, 24, 2), 256, 0, stream>>>(qkv_txt_w, qkv_img_w, wreg);
    gemm2<0, bf16_t><<<dim3(36, 12), 256, 0, stream>>>(
        n1, D_MODEL, wreg, 4608 * 1536, qkv_txt_b, qkv_img_b,
        nullptr, nullptr, 0, nullptr, nullptr, qkvb, 4608, 1536);
    // 4. RMS + RoPE -> bf16 q,k ; V transpose
    qkv_epi<<<dim3(12, 1536), 128, 0, stream>>>(qkvb, rope, qn_img, kn_img, qn_txt, kn_txt, qb, kb);
    v_tr<<<dim3(12, 24), 256, 0, stream>>>(qkvb, vt);
    // 5. attention -> o bf16
    attn_k<<<dim3(12, 24), 256, 0, stream>>>(qb, kb, vt, obuf);
    // 6. out-proj (fused txt+img) + gate + residual -> d_out
    conv_wt<1536, 1536><<<dim3(24, 24, 2), 256, 0, stream>>>(out_txt_w, out_img_w, wreg);
    gemm2<2, float><<<dim3(12, 12), 256, 0, stream>>>(
        obuf, D_MODEL, wreg, 1536 * 1536, out_txt_b, out_img_b,
        encoder, hidden, D_MODEL, emb_t + 2 * D_MODEL, emb_i + 2 * D_MODEL,
        dout, D_MODEL, 1536);
    // 7. LN2 + modulate -> bf16
    ln_mod<<<S_TOT, 256, 0, stream>>>(dout, dout + (size_t)S_TXT * D_MODEL, emb_t, emb_i, 3, 4, n1);
    // 8. MLP up + gelu -> bf16 ff
    conv_wt<1536, 6144><<<dim3(96, 24, 2), 256, 0, stream>>>(mlp_txt_w1, mlp_img_w1, wreg);
    gemm2<1, bf16_t><<<dim3(48, 12), 256, 0, stream>>>(
        n1, D_MODEL, wreg, 6144 * 1536, mlp_txt_b1, mlp_img_b1,
        nullptr, nullptr, 0, nullptr, nullptr, ffb, FF_DIM, 1536);
    // 9. MLP down + gate + residual, in place on d_out
    conv_wt<6144, 1536><<<dim3(24, 96, 2), 256, 0, stream>>>(mlp_txt_w2, mlp_img_w2, wreg);
    gemm2<2, float><<<dim3(12, 12), 256, 0, stream>>>(
        ffb, FF_DIM, wreg, 1536 * 6144, mlp_txt_b2, mlp_img_b2,
        dout, dout + (size_t)S_TXT * D_MODEL, D_MODEL,
        emb_t + 5 * D_MODEL, emb_i + 5 * D_MODEL, dout, D_MODEL, 6144);
    (void)in_sizes; (void)n_in; (void)out_size; (void)ws_size;
}

// Round 3
// 702.878 us; speedup vs baseline: 3.8476x; 2.0155x over previous
//
#include <hip/hip_runtime.h>
#include <hip/hip_bf16.h>

typedef __bf16 bf16_t;
typedef __attribute__((ext_vector_type(4))) float f32x4;
typedef __attribute__((ext_vector_type(8))) bf16_t bf16x8;
typedef __attribute__((ext_vector_type(4))) bf16_t bf16x4;
typedef __attribute__((ext_vector_type(2))) bf16_t bf16x2;

#define D_MODEL 1536
#define NH 12
#define DHD 128
#define S_TXT 512
#define S_TOT 1536
#define FF_DIM 6144

// Load an 8-element bf16 MFMA fragment: k-halves at p[0..3] and p[16..19].
__device__ inline bf16x8 ld_frag(const bf16_t* p) {
    bf16x4 a = *(const bf16x4*)p;
    bf16x4 b = *(const bf16x4*)(p + 16);
    bf16x8 r;
    r[0]=a[0]; r[1]=a[1]; r[2]=a[2]; r[3]=a[3];
    r[4]=b[0]; r[5]=b[1]; r[6]=b[2]; r[7]=b[3];
    return r;
}

// async global->LDS, 16 B per lane. LDS dest is wave-uniform base (+lane*16 by HW).
__device__ inline void gload16(const void* g, void* l) {
    __builtin_amdgcn_global_load_lds((const __attribute__((address_space(1))) unsigned int*)g,
                                     (__attribute__((address_space(3))) unsigned int*)l, 16, 0, 0);
}

// ---------------------------------------------------------------------------
// adaLN stage 1: partial dot products, K split 8 ways. grid (72,8) block 256.
// ---------------------------------------------------------------------------
__global__ __launch_bounds__(256)
void adaln_p(const float* __restrict__ temb,
             const float* __restrict__ w_img, const float* __restrict__ w_txt,
             float* __restrict__ part) {
    __shared__ float t[192];
    int tid = threadIdx.x;
    int k0 = blockIdx.y * 192;
    if (tid < 192) {
        float x = temb[k0 + tid];
        t[tid] = x / (1.0f + __expf(-x));
    }
    __syncthreads();
    int n_g = blockIdx.x * 256 + tid;
    bool img = n_g < 9216;
    const float* W = img ? w_img : w_txt;
    int n = img ? n_g : n_g - 9216;
    float acc = 0.f;
    for (int kk = 0; kk < 192; kk += 4) {
        acc += t[kk]     * W[(size_t)(k0 + kk) * 9216 + n];
        acc += t[kk + 1] * W[(size_t)(k0 + kk + 1) * 9216 + n];
        acc += t[kk + 2] * W[(size_t)(k0 + kk + 2) * 9216 + n];
        acc += t[kk + 3] * W[(size_t)(k0 + kk + 3) * 9216 + n];
    }
    part[(size_t)blockIdx.y * 18432 + n_g] = acc;
}

// adaLN stage 2: reduce + bias. grid 72 x 256.
__global__ __launch_bounds__(256)
void adaln_r(const float* __restrict__ part,
             const float* __restrict__ b_img, const float* __restrict__ b_txt,
             float* __restrict__ emb_img, float* __restrict__ emb_txt) {
    int n_g = blockIdx.x * 256 + threadIdx.x;
    float a = 0.f;
#pragma unroll
    for (int kc = 0; kc < 8; ++kc) a += part[(size_t)kc * 18432 + n_g];
    if (n_g < 9216) emb_img[n_g] = a + b_img[n_g];
    else            emb_txt[n_g - 9216] = a + b_txt[n_g - 9216];
}

// ---------------------------------------------------------------------------
// LayerNorm + modulate -> bf16. Rows 0..511 txt, 512..1535 img.
// ---------------------------------------------------------------------------
__global__ __launch_bounds__(256)
void ln_mod(const float* __restrict__ src_txt, const float* __restrict__ src_img,
            const float* __restrict__ emb_t, const float* __restrict__ emb_i,
            int sh_c, int sc_c, bf16_t* __restrict__ out) {
    int row = blockIdx.x;
    bool txt = row < S_TXT;
    const float* src = txt ? src_txt + (size_t)row * D_MODEL
                           : src_img + (size_t)(row - S_TXT) * D_MODEL;
    const float* emb = txt ? emb_t : emb_i;
    int tid = threadIdx.x;
    float2 v[3];
    float s = 0.f, sq = 0.f;
#pragma unroll
    for (int i = 0; i < 3; ++i) {
        v[i] = *(const float2*)(src + tid * 2 + 512 * i);
        s  += v[i].x + v[i].y;
        sq += v[i].x * v[i].x + v[i].y * v[i].y;
    }
#pragma unroll
    for (int off = 32; off > 0; off >>= 1) {
        s  += __shfl_down(s, off);
        sq += __shfl_down(sq, off);
    }
    __shared__ float red[8];
    int wave = tid >> 6, lane = tid & 63;
    if (lane == 0) { red[wave] = s; red[4 + wave] = sq; }
    __syncthreads();
    float ts = red[0] + red[1] + red[2] + red[3];
    float tq = red[4] + red[5] + red[6] + red[7];
    float mean = ts * (1.0f / D_MODEL);
    float var  = tq * (1.0f / D_MODEL) - mean * mean;
    float rstd = rsqrtf(var + 1e-6f);
    bf16_t* op = out + (size_t)row * D_MODEL;
#pragma unroll
    for (int i = 0; i < 3; ++i) {
        int c0 = tid * 2 + 512 * i;
        bf16x2 r;
        r[0] = (bf16_t)((v[i].x - mean) * rstd * (1.0f + emb[sc_c * D_MODEL + c0])     + emb[sh_c * D_MODEL + c0]);
        r[1] = (bf16_t)((v[i].y - mean) * rstd * (1.0f + emb[sc_c * D_MODEL + c0 + 1]) + emb[sh_c * D_MODEL + c0 + 1]);
        *(bf16x2*)(op + c0) = r;
    }
}

// ---------------------------------------------------------------------------
// Weight convert+transpose: W f32 [K][N] -> Wt bf16 [N][K]. grid (N/64,K/64,2).
// ---------------------------------------------------------------------------
template <int K, int N>
__global__ __launch_bounds__(256)
void conv_wt(const float* __restrict__ w_t, const float* __restrict__ w_i,
             bf16_t* __restrict__ dst) {
    __shared__ float tile[64][65];
    const float* src = blockIdx.z ? w_i : w_t;
    bf16_t* d = dst + (size_t)blockIdx.z * N * K;
    int bn = blockIdx.x * 64, bk = blockIdx.y * 64;
    int tid = threadIdx.x;
#pragma unroll
    for (int j = 0; j < 16; ++j) {
        int l = tid + 256 * j;
        int k = l >> 6, n = l & 63;
        tile[k][n] = src[(size_t)(bk + k) * N + bn + n];
    }
    __syncthreads();
#pragma unroll
    for (int j = 0; j < 16; ++j) {
        int l = tid + 256 * j;
        int n = l >> 6, k = l & 63;
        d[(size_t)(bn + n) * K + bk + k] = (bf16_t)tile[k][n];
    }
}

// ---------------------------------------------------------------------------
// bf16 MFMA GEMM: out(MxN) = A(MxK,bf16) @ Wt(NxK,bf16)^T.
// 128x128 tile, BK=64, 4 waves (2x2). 2-phase double-buffered pipeline
// (T3 minimum), LDS XOR-swizzle with pre-swizzled global source (T2/rule21),
// XCD-aware block swizzle (T1). Frag k-mapping identical for A and B (any
// shared k-permutation cancels in the dot product).
// EPI: 0=bias  1=bias+gelu(tanh)  2=resid + gate*(bias+acc)
// ---------------------------------------------------------------------------
template <int EPI, typename OutT>
__global__ __launch_bounds__(256)
void gemm2(const bf16_t* __restrict__ A, int lda,
           const bf16_t* __restrict__ Wt, int wimg_off,
           const float* __restrict__ bias_t, const float* __restrict__ bias_i,
           const float* __restrict__ resid_t, const float* __restrict__ resid_i, int ldr,
           const float* __restrict__ gate_t, const float* __restrict__ gate_i,
           OutT* __restrict__ out, int ldo, int K) {
    __shared__ bf16_t As[2][128 * 64];
    __shared__ bf16_t Bs[2][128 * 64];
    const int tid = threadIdx.x;

    // XCD-aware swizzle (bijective; all our grids have nwg % 8 == 0)
    const int nbx = gridDim.x;
    const int nwg = nbx * gridDim.y;
    int lb = blockIdx.y * nbx + blockIdx.x;
    if ((nwg & 7) == 0) lb = (lb & 7) * (nwg >> 3) + (lb >> 3);
    const int bm = (lb / nbx) * 128, bn = (lb % nbx) * 128;

    const bool txt = bm < S_TXT;
    const bf16_t* W = txt ? Wt : Wt + wimg_off;
    const float* bias = txt ? bias_t : bias_i;
    const int wave = tid >> 6, lane = tid & 63;
    const int wr = (wave >> 1) * 64, wc = (wave & 1) * 64;
    const int lr = lane & 15, lg = lane >> 4;

    // staging: wave w round j covers rows j*32 + w*8 + (lane>>3); source chunk
    // XOR-pre-swizzled so that a linear LDS write + XOR'd read = swizzled tile.
    const int srow = wave * 8 + (lane >> 3);
    const int csrc = ((lane & 7) ^ ((lane >> 3) & 7)) * 8;  // elem offset in row
    const bf16_t* Ab = A + (size_t)(bm + srow) * lda + csrc;
    const bf16_t* Wb = W + (size_t)(bn + srow) * K + csrc;
    const int ldst = (wave * 8) * 64;  // + j*32*64 per round

    f32x4 acc[4][4] = {};
    const int nt = K >> 6;

    auto stage = [&](int buf, int t) {
#pragma unroll
        for (int j = 0; j < 4; ++j) {
            gload16(Ab + (size_t)j * 32 * lda + t * 64, &As[buf][ldst + j * 2048]);
            gload16(Wb + (size_t)j * 32 * K   + t * 64, &Bs[buf][ldst + j * 2048]);
        }
    };

    stage(0, 0);
    asm volatile("s_waitcnt vmcnt(0)" ::: "memory");
    __builtin_amdgcn_s_barrier();

    int cur = 0;
    for (int t = 0; t < nt; ++t) {
        if (t + 1 < nt) stage(cur ^ 1, t + 1);   // issue next tile's loads first
#pragma unroll
        for (int kk = 0; kk < 2; ++kk) {
            bf16x8 af[4], bfm[4];
#pragma unroll
            for (int m = 0; m < 4; ++m) {
                int rr = wr + m * 16 + lr;
                af[m] = *(const bf16x8*)&As[cur][rr * 64 + (((kk * 4 + lg) ^ (lr & 7)) * 8)];
            }
#pragma unroll
            for (int n = 0; n < 4; ++n) {
                int rr = wc + n * 16 + lr;
                bfm[n] = *(const bf16x8*)&Bs[cur][rr * 64 + (((kk * 4 + lg) ^ (lr & 7)) * 8)];
            }
#pragma unroll
            for (int m = 0; m < 4; ++m)
#pragma unroll
                for (int n = 0; n < 4; ++n)
                    acc[m][n] = __builtin_amdgcn_mfma_f32_16x16x32_bf16(af[m], bfm[n], acc[m][n], 0, 0, 0);
        }
        asm volatile("s_waitcnt vmcnt(0)" ::: "memory");  // next tile's LDS writes landed
        __builtin_amdgcn_s_barrier();                     // all waves done reading cur
        cur ^= 1;
    }

    const float* gate  = txt ? gate_t : gate_i;
    const float* resid = txt ? resid_t : resid_i;
    const int rbase = txt ? 0 : S_TXT;
#pragma unroll
    for (int m = 0; m < 4; ++m) {
#pragma unroll
        for (int r = 0; r < 4; ++r) {
            int grow = bm + wr + m * 16 + lg * 4 + r;
#pragma unroll
            for (int n = 0; n < 4; ++n) {
                int gcol = bn + wc + n * 16 + lr;
                float v = acc[m][n][r] + bias[gcol];
                if constexpr (EPI == 1) {
                    float x = v;
                    float th = tanhf(0.7978845608028654f * (x + 0.044715f * x * x * x));
                    v = 0.5f * x * (1.0f + th);
                } else if constexpr (EPI == 2) {
                    v = resid[(size_t)(grow - rbase) * ldr + gcol] + gate[gcol] * v;
                }
                out[(size_t)grow * ldo + gcol] = (OutT)v;
            }
        }
    }
}

// ---------------------------------------------------------------------------
// QKV epilogue: RMS-norm(q,k) + RoPE + fold 1/sqrt(DH) into q; bf16 in/out.
// grid (12, 1536), block 128.
// ---------------------------------------------------------------------------
__global__ __launch_bounds__(128)
void qkv_epi(const bf16_t* __restrict__ qkv, const float* __restrict__ rope,
             const float* __restrict__ qn_i, const float* __restrict__ kn_i,
             const float* __restrict__ qn_t, const float* __restrict__ kn_t,
             bf16_t* __restrict__ qb, bf16_t* __restrict__ kb) {
    int h = blockIdx.x, s = blockIdx.y, dh = threadIdx.x;
    bool txt = s < S_TXT;
    const float* qn = txt ? qn_t : qn_i;
    const float* kn = txt ? kn_t : kn_i;
    const bf16_t* base = qkv + (size_t)s * 4608 + h * DHD + dh;
    float q = (float)base[0];
    float k = (float)base[D_MODEL];
    float qs = q * q, ks = k * k;
#pragma unroll
    for (int off = 32; off > 0; off >>= 1) {
        qs += __shfl_down(qs, off);
        ks += __shfl_down(ks, off);
    }
    __shared__ float red[4];
    if ((threadIdx.x & 63) == 0) {
        red[(threadIdx.x >> 6) * 2]     = qs;
        red[(threadIdx.x >> 6) * 2 + 1] = ks;
    }
    __syncthreads();
    float qr = rsqrtf((red[0] + red[2]) * (1.0f / DHD) + 1e-6f);
    float kr = rsqrtf((red[1] + red[3]) * (1.0f / DHD) + 1e-6f);
    q = q * qr * qn[dh];
    k = k * kr * kn[dh];
    int i = dh & 1, d = dh >> 1;
    const float* rp = rope + ((size_t)s * 64 + d) * 4 + i * 2;
    float r0 = rp[0], r1 = rp[1];
    float qo = __shfl_xor(q, 1), ko = __shfl_xor(k, 1);
    float q0 = i ? qo : q, q1 = i ? q : qo;
    float k0 = i ? ko : k, k1 = i ? k : ko;
    float qq = r0 * q0 + r1 * q1;
    float kk = r0 * k0 + r1 * k1;
    size_t idx = ((size_t)h * S_TOT + s) * DHD + dh;
    qb[idx] = (bf16_t)(qq * 0.08838834764831845f);  // 1/sqrt(128)
    kb[idx] = (bf16_t)kk;
}

// ---------------------------------------------------------------------------
// V transpose: per-head vT[DH][S] bf16. grid (12, 24), block 256.
// ---------------------------------------------------------------------------
__global__ __launch_bounds__(256)
void v_tr(const bf16_t* __restrict__ qkv, bf16_t* __restrict__ vt) {
    __shared__ bf16_t tile[64][130];
    int h = blockIdx.x, sb = blockIdx.y * 64;
    int tid = threadIdx.x;
#pragma unroll
    for (int j = 0; j < 32; ++j) {
        int linear = tid + 256 * j;
        int sl = linear >> 7, dh = linear & 127;
        tile[sl][dh] = qkv[(size_t)(sb + sl) * 4608 + 2 * D_MODEL + h * DHD + dh];
    }
    __syncthreads();
#pragma unroll
    for (int j = 0; j < 32; ++j) {
        int linear = tid + 256 * j;
        int dh = linear >> 6, sl = linear & 63;
        vt[((size_t)h * DHD + dh) * S_TOT + sb + sl] = tile[sl][dh];
    }
}

// ---------------------------------------------------------------------------
// Flash attention: grid (12, 24) = (head, q-block 64), 4 waves x 16 q-rows.
// ---------------------------------------------------------------------------
__global__ __launch_bounds__(256)
void attn_k(const bf16_t* __restrict__ qb, const bf16_t* __restrict__ kb,
            const bf16_t* __restrict__ vt, bf16_t* __restrict__ o) {
    __shared__ bf16_t P[4][16][68];
    int h = blockIdx.x, q0 = blockIdx.y * 64;
    int tid = threadIdx.x, wave = tid >> 6, lane = tid & 63;
    int lr = lane & 15, lg = lane >> 4;
    const bf16_t* Qp = qb + ((size_t)h * S_TOT + q0 + wave * 16 + lr) * DHD;
    bf16x8 qf[4];
#pragma unroll
    for (int kk = 0; kk < 4; ++kk) qf[kk] = ld_frag(Qp + kk * 32 + lg * 4);
    f32x4 of[8] = {};
    float m[4] = {-1e30f, -1e30f, -1e30f, -1e30f};
    float l[4] = {};
    for (int kb0 = 0; kb0 < S_TOT; kb0 += 64) {
        f32x4 sf[4] = {};
#pragma unroll
        for (int n = 0; n < 4; ++n) {
            const bf16_t* Kp = kb + ((size_t)h * S_TOT + kb0 + n * 16 + lr) * DHD;
#pragma unroll
            for (int kk = 0; kk < 4; ++kk) {
                bf16x8 kf = ld_frag(Kp + kk * 32 + lg * 4);
                sf[n] = __builtin_amdgcn_mfma_f32_16x16x32_bf16(qf[kk], kf, sf[n], 0, 0, 0);
            }
        }
        float bm[4], alpha[4], rs[4];
#pragma unroll
        for (int r = 0; r < 4; ++r)
            bm[r] = fmaxf(fmaxf(sf[0][r], sf[1][r]), fmaxf(sf[2][r], sf[3][r]));
#pragma unroll
        for (int mask = 1; mask < 16; mask <<= 1)
#pragma unroll
            for (int r = 0; r < 4; ++r) bm[r] = fmaxf(bm[r], __shfl_xor(bm[r], mask));
#pragma unroll
        for (int r = 0; r < 4; ++r) {
            float mn = fmaxf(m[r], bm[r]);
            alpha[r] = __expf(m[r] - mn);
            m[r] = mn;
            rs[r] = 0.f;
        }
#pragma unroll
        for (int n = 0; n < 4; ++n)
#pragma unroll
            for (int r = 0; r < 4; ++r) {
                float p = __expf(sf[n][r] - m[r]);
                rs[r] += p;
                P[wave][lg * 4 + r][n * 16 + lr] = (bf16_t)p;
            }
#pragma unroll
        for (int mask = 1; mask < 16; mask <<= 1)
#pragma unroll
            for (int r = 0; r < 4; ++r) rs[r] += __shfl_xor(rs[r], mask);
#pragma unroll
        for (int r = 0; r < 4; ++r) l[r] = l[r] * alpha[r] + rs[r];
#pragma unroll
        for (int nf = 0; nf < 8; ++nf)
#pragma unroll
            for (int r = 0; r < 4; ++r) of[nf][r] *= alpha[r];
        __syncthreads();
#pragma unroll
        for (int kk2 = 0; kk2 < 2; ++kk2) {
            bf16x8 pf = ld_frag(&P[wave][lr][kk2 * 32 + lg * 4]);
#pragma unroll
            for (int nf = 0; nf < 8; ++nf) {
                const bf16_t* Vp = vt + ((size_t)h * DHD + nf * 16 + lr) * S_TOT + kb0 + kk2 * 32 + lg * 4;
                bf16x8 vf = ld_frag(Vp);
                of[nf] = __builtin_amdgcn_mfma_f32_16x16x32_bf16(pf, vf, of[nf], 0, 0, 0);
            }
        }
        __syncthreads();
    }
    int orow = q0 + wave * 16 + lg * 4;
#pragma unroll
    for (int r = 0; r < 4; ++r) {
        float inv = 1.0f / l[r];
#pragma unroll
        for (int nf = 0; nf < 8; ++nf)
            o[(size_t)(orow + r) * D_MODEL + h * DHD + nf * 16 + lr] = (bf16_t)(of[nf][r] * inv);
    }
}

// ---------------------------------------------------------------------------
extern "C" void kernel_launch(void* const* d_in, const int* in_sizes, int n_in,
                              void* d_out, int out_size, void* d_ws, size_t ws_size,
                              hipStream_t stream) {
    const float* hidden  = (const float*)d_in[0];
    const float* encoder = (const float*)d_in[1];
    const float* temb    = (const float*)d_in[2];
    const float* rope    = (const float*)d_in[3];
    const float* adaln_img_w = (const float*)d_in[4];
    const float* adaln_img_b = (const float*)d_in[5];
    const float* adaln_txt_w = (const float*)d_in[6];
    const float* adaln_txt_b = (const float*)d_in[7];
    const float* qkv_img_w = (const float*)d_in[8];
    const float* qkv_img_b = (const float*)d_in[9];
    const float* qkv_txt_w = (const float*)d_in[10];
    const float* qkv_txt_b = (const float*)d_in[11];
    const float* qn_img = (const float*)d_in[12];
    const float* kn_img = (const float*)d_in[13];
    const float* qn_txt = (const float*)d_in[14];
    const float* kn_txt = (const float*)d_in[15];
    const float* out_img_w = (const float*)d_in[16];
    const float* out_img_b = (const float*)d_in[17];
    const float* out_txt_w = (const float*)d_in[18];
    const float* out_txt_b = (const float*)d_in[19];
    const float* mlp_img_w1 = (const float*)d_in[20];
    const float* mlp_img_b1 = (const float*)d_in[21];
    const float* mlp_img_w2 = (const float*)d_in[22];
    const float* mlp_img_b2 = (const float*)d_in[23];
    const float* mlp_txt_w1 = (const float*)d_in[24];
    const float* mlp_txt_b1 = (const float*)d_in[25];
    const float* mlp_txt_w2 = (const float*)d_in[26];
    const float* mlp_txt_b2 = (const float*)d_in[27];
    float* dout = (float*)d_out;
    char* wsb = (char*)d_ws;

    // ws layout (byte offsets), total 70,852,608 B = 67.6 MB.
    float*  emb_i = (float*)(wsb);                    // 9216 f32
    float*  emb_t = (float*)(wsb + 36864);            // 9216 f32
    bf16_t* wreg  = (bf16_t*)(wsb + 73728);           // 18,874,368 bf16 (reused per stage)
    float*  part  = (float*)(wsb + 73728);            // adaln partials overlay (8x18432 f32)
    bf16_t* n1    = (bf16_t*)(wsb + 37822464);        // 1536x1536 bf16 (LN1, later LN2)
    bf16_t* qkvb  = (bf16_t*)(wsb + 42541056);        // 1536x4608 bf16
    bf16_t* obuf  = qkvb;                             // alias (qkvb dead after epi/v_tr)
    bf16_t* ffb   = qkvb + 2359296;                   // 1536x6144 bf16, overlays dead qb/kb
    bf16_t* qb    = (bf16_t*)(wsb + 56696832);        // 12x1536x128 bf16
    bf16_t* kb    = (bf16_t*)(wsb + 61415424);
    bf16_t* vt    = (bf16_t*)(wsb + 66134016);

    // 1. adaLN (K-split + reduce)
    adaln_p<<<dim3(72, 8), 256, 0, stream>>>(temb, adaln_img_w, adaln_txt_w, part);
    adaln_r<<<72, 256, 0, stream>>>(part, adaln_img_b, adaln_txt_b, emb_i, emb_t);
    // 2. LN1 + modulate -> bf16
    ln_mod<<<S_TOT, 256, 0, stream>>>(encoder, hidden, emb_t, emb_i, 0, 1, n1);
    // 3. QKV: convert weights, fused GEMM
    conv_wt<1536, 4608><<<dim3(72, 24, 2), 256, 0, stream>>>(qkv_txt_w, qkv_img_w, wreg);
    gemm2<0, bf16_t><<<dim3(36, 12), 256, 0, stream>>>(
        n1, D_MODEL, wreg, 4608 * 1536, qkv_txt_b, qkv_img_b,
        nullptr, nullptr, 0, nullptr, nullptr, qkvb, 4608, 1536);
    // 4. RMS + RoPE -> bf16 q,k ; V transpose
    qkv_epi<<<dim3(12, 1536), 128, 0, stream>>>(qkvb, rope, qn_img, kn_img, qn_txt, kn_txt, qb, kb);
    v_tr<<<dim3(12, 24), 256, 0, stream>>>(qkvb, vt);
    // 5. attention -> o bf16
    attn_k<<<dim3(12, 24), 256, 0, stream>>>(qb, kb, vt, obuf);
    // 6. out-proj (fused txt+img) + gate + residual -> d_out
    conv_wt<1536, 1536><<<dim3(24, 24, 2), 256, 0, stream>>>(out_txt_w, out_img_w, wreg);
    gemm2<2, float><<<dim3(12, 12), 256, 0, stream>>>(
        obuf, D_MODEL, wreg, 1536 * 1536, out_txt_b, out_img_b,
        encoder, hidden, D_MODEL, emb_t + 2 * D_MODEL, emb_i + 2 * D_MODEL,
        dout, D_MODEL, 1536);
    // 7. LN2 + modulate -> bf16
    ln_mod<<<S_TOT, 256, 0, stream>>>(dout, dout + (size_t)S_TXT * D_MODEL, emb_t, emb_i, 3, 4, n1);
    // 8. MLP up + gelu -> bf16 ff
    conv_wt<1536, 6144><<<dim3(96, 24, 2), 256, 0, stream>>>(mlp_txt_w1, mlp_img_w1, wreg);
    gemm2<1, bf16_t><<<dim3(48, 12), 256, 0, stream>>>(
        n1, D_MODEL, wreg, 6144 * 1536, mlp_txt_b1, mlp_img_b1,
        nullptr, nullptr, 0, nullptr, nullptr, ffb, FF_DIM, 1536);
    // 9. MLP down + gate + residual, in place on d_out
    conv_wt<6144, 1536><<<dim3(24, 96, 2), 256, 0, stream>>>(mlp_txt_w2, mlp_img_w2, wreg);
    gemm2<2, float><<<dim3(12, 12), 256, 0, stream>>>(
        ffb, FF_DIM, wreg, 1536 * 6144, mlp_txt_b2, mlp_img_b2,
        dout, dout + (size_t)S_TXT * D_MODEL, D_MODEL,
        emb_t + 5 * D_MODEL, emb_i + 5 * D_MODEL, dout, D_MODEL, 6144);
    (void)in_sizes; (void)n_in; (void)out_size; (void)ws_size;
}

// Round 4
// 606.309 us; speedup vs baseline: 4.4604x; 1.1593x over previous
//
#include <hip/hip_runtime.h>
#include <hip/hip_bf16.h>

typedef __bf16 bf16_t;
typedef __attribute__((ext_vector_type(4))) float f32x4;
typedef __attribute__((ext_vector_type(8))) bf16_t bf16x8;
typedef __attribute__((ext_vector_type(4))) bf16_t bf16x4;
typedef __attribute__((ext_vector_type(2))) bf16_t bf16x2;

#define D_MODEL 1536
#define NH 12
#define DHD 128
#define S_TXT 512
#define S_TOT 1536
#define FF_DIM 6144
#define KVSPLIT 4
#define HQB 288   // 12 heads * 24 q-blocks

// Load an 8-element bf16 MFMA fragment: k-halves at p[0..3] and p[16..19].
__device__ inline bf16x8 ld_frag(const bf16_t* p) {
    bf16x4 a = *(const bf16x4*)p;
    bf16x4 b = *(const bf16x4*)(p + 16);
    bf16x8 r;
    r[0]=a[0]; r[1]=a[1]; r[2]=a[2]; r[3]=a[3];
    r[4]=b[0]; r[5]=b[1]; r[6]=b[2]; r[7]=b[3];
    return r;
}

// async global->LDS, 16 B per lane. LDS dest is wave-uniform base (+lane*16 by HW).
__device__ inline void gload16(const void* g, void* l) {
    __builtin_amdgcn_global_load_lds((const __attribute__((address_space(1))) unsigned int*)g,
                                     (__attribute__((address_space(3))) unsigned int*)l, 16, 0, 0);
}

// ---------------------------------------------------------------------------
// adaLN stage 1: partial dot products, K split 8 ways. grid (72,8) block 256.
// ---------------------------------------------------------------------------
__global__ __launch_bounds__(256)
void adaln_p(const float* __restrict__ temb,
             const float* __restrict__ w_img, const float* __restrict__ w_txt,
             float* __restrict__ part) {
    __shared__ float t[192];
    int tid = threadIdx.x;
    int k0 = blockIdx.y * 192;
    if (tid < 192) {
        float x = temb[k0 + tid];
        t[tid] = x / (1.0f + __expf(-x));
    }
    __syncthreads();
    int n_g = blockIdx.x * 256 + tid;
    bool img = n_g < 9216;
    const float* W = img ? w_img : w_txt;
    int n = img ? n_g : n_g - 9216;
    float acc = 0.f;
    for (int kk = 0; kk < 192; kk += 4) {
        acc += t[kk]     * W[(size_t)(k0 + kk) * 9216 + n];
        acc += t[kk + 1] * W[(size_t)(k0 + kk + 1) * 9216 + n];
        acc += t[kk + 2] * W[(size_t)(k0 + kk + 2) * 9216 + n];
        acc += t[kk + 3] * W[(size_t)(k0 + kk + 3) * 9216 + n];
    }
    part[(size_t)blockIdx.y * 18432 + n_g] = acc;
}

// adaLN stage 2: reduce + bias. grid 72 x 256.
__global__ __launch_bounds__(256)
void adaln_r(const float* __restrict__ part,
             const float* __restrict__ b_img, const float* __restrict__ b_txt,
             float* __restrict__ emb_img, float* __restrict__ emb_txt) {
    int n_g = blockIdx.x * 256 + threadIdx.x;
    float a = 0.f;
#pragma unroll
    for (int kc = 0; kc < 8; ++kc) a += part[(size_t)kc * 18432 + n_g];
    if (n_g < 9216) emb_img[n_g] = a + b_img[n_g];
    else            emb_txt[n_g - 9216] = a + b_txt[n_g - 9216];
}

// ---------------------------------------------------------------------------
// LayerNorm + modulate -> bf16. Rows 0..511 txt, 512..1535 img.
// ---------------------------------------------------------------------------
__global__ __launch_bounds__(256)
void ln_mod(const float* __restrict__ src_txt, const float* __restrict__ src_img,
            const float* __restrict__ emb_t, const float* __restrict__ emb_i,
            int sh_c, int sc_c, bf16_t* __restrict__ out) {
    int row = blockIdx.x;
    bool txt = row < S_TXT;
    const float* src = txt ? src_txt + (size_t)row * D_MODEL
                           : src_img + (size_t)(row - S_TXT) * D_MODEL;
    const float* emb = txt ? emb_t : emb_i;
    int tid = threadIdx.x;
    float2 v[3];
    float s = 0.f, sq = 0.f;
#pragma unroll
    for (int i = 0; i < 3; ++i) {
        v[i] = *(const float2*)(src + tid * 2 + 512 * i);
        s  += v[i].x + v[i].y;
        sq += v[i].x * v[i].x + v[i].y * v[i].y;
    }
#pragma unroll
    for (int off = 32; off > 0; off >>= 1) {
        s  += __shfl_down(s, off);
        sq += __shfl_down(sq, off);
    }
    __shared__ float red[8];
    int wave = tid >> 6, lane = tid & 63;
    if (lane == 0) { red[wave] = s; red[4 + wave] = sq; }
    __syncthreads();
    float ts = red[0] + red[1] + red[2] + red[3];
    float tq = red[4] + red[5] + red[6] + red[7];
    float mean = ts * (1.0f / D_MODEL);
    float var  = tq * (1.0f / D_MODEL) - mean * mean;
    float rstd = rsqrtf(var + 1e-6f);
    bf16_t* op = out + (size_t)row * D_MODEL;
#pragma unroll
    for (int i = 0; i < 3; ++i) {
        int c0 = tid * 2 + 512 * i;
        bf16x2 r;
        r[0] = (bf16_t)((v[i].x - mean) * rstd * (1.0f + emb[sc_c * D_MODEL + c0])     + emb[sh_c * D_MODEL + c0]);
        r[1] = (bf16_t)((v[i].y - mean) * rstd * (1.0f + emb[sc_c * D_MODEL + c0 + 1]) + emb[sh_c * D_MODEL + c0 + 1]);
        *(bf16x2*)(op + c0) = r;
    }
}

// ---------------------------------------------------------------------------
// Weight convert+transpose: W f32 [K][N] -> Wt bf16 [N][K]. grid (N/64,K/64,2).
// ---------------------------------------------------------------------------
template <int K, int N>
__global__ __launch_bounds__(256)
void conv_wt(const float* __restrict__ w_t, const float* __restrict__ w_i,
             bf16_t* __restrict__ dst) {
    __shared__ float tile[64][65];
    const float* src = blockIdx.z ? w_i : w_t;
    bf16_t* d = dst + (size_t)blockIdx.z * N * K;
    int bn = blockIdx.x * 64, bk = blockIdx.y * 64;
    int tid = threadIdx.x;
#pragma unroll
    for (int j = 0; j < 16; ++j) {
        int l = tid + 256 * j;
        int k = l >> 6, n = l & 63;
        tile[k][n] = src[(size_t)(bk + k) * N + bn + n];
    }
    __syncthreads();
#pragma unroll
    for (int j = 0; j < 16; ++j) {
        int l = tid + 256 * j;
        int n = l >> 6, k = l & 63;
        d[(size_t)(bn + n) * K + bk + k] = (bf16_t)tile[k][n];
    }
}

// ---------------------------------------------------------------------------
// bf16 MFMA GEMM: out(MxN) = A(MxK,bf16) @ Wt(NxK,bf16)^T.
// 128x128 tile, BK=64, 4 waves (2x2). 2-phase dbuf pipeline (T3 min),
// LDS XOR-swizzle via pre-swizzled global source (T2/rule21), XCD swizzle (T1).
// EPI: 0=bias  1=bias+gelu(tanh)  2=resid + gate*(bias+acc)
// ---------------------------------------------------------------------------
template <int EPI, typename OutT>
__global__ __launch_bounds__(256)
void gemm2(const bf16_t* __restrict__ A, int lda,
           const bf16_t* __restrict__ Wt, int wimg_off,
           const float* __restrict__ bias_t, const float* __restrict__ bias_i,
           const float* __restrict__ resid_t, const float* __restrict__ resid_i, int ldr,
           const float* __restrict__ gate_t, const float* __restrict__ gate_i,
           OutT* __restrict__ out, int ldo, int K) {
    __shared__ bf16_t As[2][128 * 64];
    __shared__ bf16_t Bs[2][128 * 64];
    const int tid = threadIdx.x;

    const int nbx = gridDim.x;
    const int nwg = nbx * gridDim.y;
    int lb = blockIdx.y * nbx + blockIdx.x;
    if ((nwg & 7) == 0) lb = (lb & 7) * (nwg >> 3) + (lb >> 3);
    const int bm = (lb / nbx) * 128, bn = (lb % nbx) * 128;

    const bool txt = bm < S_TXT;
    const bf16_t* W = txt ? Wt : Wt + wimg_off;
    const float* bias = txt ? bias_t : bias_i;
    const int wave = tid >> 6, lane = tid & 63;
    const int wr = (wave >> 1) * 64, wc = (wave & 1) * 64;
    const int lr = lane & 15, lg = lane >> 4;

    const int srow = wave * 8 + (lane >> 3);
    const int csrc = ((lane & 7) ^ ((lane >> 3) & 7)) * 8;
    const bf16_t* Ab = A + (size_t)(bm + srow) * lda + csrc;
    const bf16_t* Wb = W + (size_t)(bn + srow) * K + csrc;
    const int ldst = (wave * 8) * 64;

    f32x4 acc[4][4] = {};
    const int nt = K >> 6;

    auto stage = [&](int buf, int t) {
#pragma unroll
        for (int j = 0; j < 4; ++j) {
            gload16(Ab + (size_t)j * 32 * lda + t * 64, &As[buf][ldst + j * 2048]);
            gload16(Wb + (size_t)j * 32 * K   + t * 64, &Bs[buf][ldst + j * 2048]);
        }
    };

    stage(0, 0);
    asm volatile("s_waitcnt vmcnt(0)" ::: "memory");
    __builtin_amdgcn_s_barrier();

    int cur = 0;
    for (int t = 0; t < nt; ++t) {
        if (t + 1 < nt) stage(cur ^ 1, t + 1);
#pragma unroll
        for (int kk = 0; kk < 2; ++kk) {
            bf16x8 af[4], bfm[4];
#pragma unroll
            for (int m = 0; m < 4; ++m) {
                int rr = wr + m * 16 + lr;
                af[m] = *(const bf16x8*)&As[cur][rr * 64 + (((kk * 4 + lg) ^ (lr & 7)) * 8)];
            }
#pragma unroll
            for (int n = 0; n < 4; ++n) {
                int rr = wc + n * 16 + lr;
                bfm[n] = *(const bf16x8*)&Bs[cur][rr * 64 + (((kk * 4 + lg) ^ (lr & 7)) * 8)];
            }
#pragma unroll
            for (int m = 0; m < 4; ++m)
#pragma unroll
                for (int n = 0; n < 4; ++n)
                    acc[m][n] = __builtin_amdgcn_mfma_f32_16x16x32_bf16(af[m], bfm[n], acc[m][n], 0, 0, 0);
        }
        asm volatile("s_waitcnt vmcnt(0)" ::: "memory");
        __builtin_amdgcn_s_barrier();
        cur ^= 1;
    }

    const float* gate  = txt ? gate_t : gate_i;
    const float* resid = txt ? resid_t : resid_i;
    const int rbase = txt ? 0 : S_TXT;
#pragma unroll
    for (int m = 0; m < 4; ++m) {
#pragma unroll
        for (int r = 0; r < 4; ++r) {
            int grow = bm + wr + m * 16 + lg * 4 + r;
#pragma unroll
            for (int n = 0; n < 4; ++n) {
                int gcol = bn + wc + n * 16 + lr;
                float v = acc[m][n][r] + bias[gcol];
                if constexpr (EPI == 1) {
                    float x = v;
                    float th = tanhf(0.7978845608028654f * (x + 0.044715f * x * x * x));
                    v = 0.5f * x * (1.0f + th);
                } else if constexpr (EPI == 2) {
                    v = resid[(size_t)(grow - rbase) * ldr + gcol] + gate[gcol] * v;
                }
                out[(size_t)grow * ldo + gcol] = (OutT)v;
            }
        }
    }
}

// ---------------------------------------------------------------------------
// gemm3: same structure, tile 128x64 (TN=64) for N=1536 GEMMs -> 288 blocks.
// EPI=2 only: out = resid + gate*(bias+acc), f32 out. LDS 48 KB -> 3 blk/CU.
// ---------------------------------------------------------------------------
__global__ __launch_bounds__(256)
void gemm3(const bf16_t* __restrict__ A, int lda,
           const bf16_t* __restrict__ Wt, int wimg_off,
           const float* __restrict__ bias_t, const float* __restrict__ bias_i,
           const float* __restrict__ resid_t, const float* __restrict__ resid_i, int ldr,
           const float* __restrict__ gate_t, const float* __restrict__ gate_i,
           float* __restrict__ out, int ldo, int K) {
    __shared__ bf16_t As[2][128 * 64];
    __shared__ bf16_t Bs[2][64 * 64];
    const int tid = threadIdx.x;

    const int nbx = gridDim.x;                 // 24 N-tiles
    const int nwg = nbx * gridDim.y;
    int lb = blockIdx.y * nbx + blockIdx.x;
    if ((nwg & 7) == 0) lb = (lb & 7) * (nwg >> 3) + (lb >> 3);
    const int bm = (lb / nbx) * 128, bn = (lb % nbx) * 64;

    const bool txt = bm < S_TXT;
    const bf16_t* W = txt ? Wt : Wt + wimg_off;
    const float* bias = txt ? bias_t : bias_i;
    const int wave = tid >> 6, lane = tid & 63;
    const int wr = (wave >> 1) * 64, wc = (wave & 1) * 32;
    const int lr = lane & 15, lg = lane >> 4;

    const int srow = wave * 8 + (lane >> 3);
    const int csrc = ((lane & 7) ^ ((lane >> 3) & 7)) * 8;
    const bf16_t* Ab = A + (size_t)(bm + srow) * lda + csrc;
    const bf16_t* Wb = W + (size_t)(bn + srow) * K + csrc;
    const int ldst = (wave * 8) * 64;

    f32x4 acc[4][2] = {};
    const int nt = K >> 6;

    auto stage = [&](int buf, int t) {
#pragma unroll
        for (int j = 0; j < 4; ++j)
            gload16(Ab + (size_t)j * 32 * lda + t * 64, &As[buf][ldst + j * 2048]);
#pragma unroll
        for (int j = 0; j < 2; ++j)
            gload16(Wb + (size_t)j * 32 * K + t * 64, &Bs[buf][ldst + j * 2048]);
    };

    stage(0, 0);
    asm volatile("s_waitcnt vmcnt(0)" ::: "memory");
    __builtin_amdgcn_s_barrier();

    int cur = 0;
    for (int t = 0; t < nt; ++t) {
        if (t + 1 < nt) stage(cur ^ 1, t + 1);
#pragma unroll
        for (int kk = 0; kk < 2; ++kk) {
            bf16x8 af[4], bfm[2];
#pragma unroll
            for (int m = 0; m < 4; ++m) {
                int rr = wr + m * 16 + lr;
                af[m] = *(const bf16x8*)&As[cur][rr * 64 + (((kk * 4 + lg) ^ (lr & 7)) * 8)];
            }
#pragma unroll
            for (int n = 0; n < 2; ++n) {
                int rr = wc + n * 16 + lr;
                bfm[n] = *(const bf16x8*)&Bs[cur][rr * 64 + (((kk * 4 + lg) ^ (lr & 7)) * 8)];
            }
#pragma unroll
            for (int m = 0; m < 4; ++m)
#pragma unroll
                for (int n = 0; n < 2; ++n)
                    acc[m][n] = __builtin_amdgcn_mfma_f32_16x16x32_bf16(af[m], bfm[n], acc[m][n], 0, 0, 0);
        }
        asm volatile("s_waitcnt vmcnt(0)" ::: "memory");
        __builtin_amdgcn_s_barrier();
        cur ^= 1;
    }

    const float* gate  = txt ? gate_t : gate_i;
    const float* resid = txt ? resid_t : resid_i;
    const int rbase = txt ? 0 : S_TXT;
#pragma unroll
    for (int m = 0; m < 4; ++m) {
#pragma unroll
        for (int r = 0; r < 4; ++r) {
            int grow = bm + wr + m * 16 + lg * 4 + r;
#pragma unroll
            for (int n = 0; n < 2; ++n) {
                int gcol = bn + wc + n * 16 + lr;
                float v = acc[m][n][r] + bias[gcol];
                v = resid[(size_t)(grow - rbase) * ldr + gcol] + gate[gcol] * v;
                out[(size_t)grow * ldo + gcol] = v;
            }
        }
    }
}

// ---------------------------------------------------------------------------
// QKV epilogue: RMS-norm(q,k) + RoPE + fold 1/sqrt(DH) into q; bf16 in/out.
// ---------------------------------------------------------------------------
__global__ __launch_bounds__(128)
void qkv_epi(const bf16_t* __restrict__ qkv, const float* __restrict__ rope,
             const float* __restrict__ qn_i, const float* __restrict__ kn_i,
             const float* __restrict__ qn_t, const float* __restrict__ kn_t,
             bf16_t* __restrict__ qb, bf16_t* __restrict__ kb) {
    int h = blockIdx.x, s = blockIdx.y, dh = threadIdx.x;
    bool txt = s < S_TXT;
    const float* qn = txt ? qn_t : qn_i;
    const float* kn = txt ? kn_t : kn_i;
    const bf16_t* base = qkv + (size_t)s * 4608 + h * DHD + dh;
    float q = (float)base[0];
    float k = (float)base[D_MODEL];
    float qs = q * q, ks = k * k;
#pragma unroll
    for (int off = 32; off > 0; off >>= 1) {
        qs += __shfl_down(qs, off);
        ks += __shfl_down(ks, off);
    }
    __shared__ float red[4];
    if ((threadIdx.x & 63) == 0) {
        red[(threadIdx.x >> 6) * 2]     = qs;
        red[(threadIdx.x >> 6) * 2 + 1] = ks;
    }
    __syncthreads();
    float qr = rsqrtf((red[0] + red[2]) * (1.0f / DHD) + 1e-6f);
    float kr = rsqrtf((red[1] + red[3]) * (1.0f / DHD) + 1e-6f);
    q = q * qr * qn[dh];
    k = k * kr * kn[dh];
    int i = dh & 1, d = dh >> 1;
    const float* rp = rope + ((size_t)s * 64 + d) * 4 + i * 2;
    float r0 = rp[0], r1 = rp[1];
    float qo = __shfl_xor(q, 1), ko = __shfl_xor(k, 1);
    float q0 = i ? qo : q, q1 = i ? q : qo;
    float k0 = i ? ko : k, k1 = i ? k : ko;
    float qq = r0 * q0 + r1 * q1;
    float kk = r0 * k0 + r1 * k1;
    size_t idx = ((size_t)h * S_TOT + s) * DHD + dh;
    qb[idx] = (bf16_t)(qq * 0.08838834764831845f);  // 1/sqrt(128)
    kb[idx] = (bf16_t)kk;
}

// ---------------------------------------------------------------------------
// V transpose: per-head vT[DH][S] bf16. grid (12, 24), block 256.
// ---------------------------------------------------------------------------
__global__ __launch_bounds__(256)
void v_tr(const bf16_t* __restrict__ qkv, bf16_t* __restrict__ vt) {
    __shared__ bf16_t tile[64][130];
    int h = blockIdx.x, sb = blockIdx.y * 64;
    int tid = threadIdx.x;
#pragma unroll
    for (int j = 0; j < 32; ++j) {
        int linear = tid + 256 * j;
        int sl = linear >> 7, dh = linear & 127;
        tile[sl][dh] = qkv[(size_t)(sb + sl) * 4608 + 2 * D_MODEL + h * DHD + dh];
    }
    __syncthreads();
#pragma unroll
    for (int j = 0; j < 32; ++j) {
        int linear = tid + 256 * j;
        int dh = linear >> 6, sl = linear & 63;
        vt[((size_t)h * DHD + dh) * S_TOT + sb + sl] = tile[sl][dh];
    }
}

// ---------------------------------------------------------------------------
// Flash attention, KV-split: grid (12, 24, KVSPLIT). Each block does 384 KV
// positions, writes un-normalized partial O + per-row (m,l). 4 waves x 16 rows.
// ---------------------------------------------------------------------------
__global__ __launch_bounds__(256)
void attn_k(const bf16_t* __restrict__ qbuf, const bf16_t* __restrict__ kbuf,
            const bf16_t* __restrict__ vt,
            float* __restrict__ part_o, float* __restrict__ part_ml) {
    __shared__ bf16_t P[4][16][68];
    int h = blockIdx.x, qblk = blockIdx.y, z = blockIdx.z;
    int q0 = qblk * 64;
    int tid = threadIdx.x, wave = tid >> 6, lane = tid & 63;
    int lr = lane & 15, lg = lane >> 4;
    const bf16_t* Qp = qbuf + ((size_t)h * S_TOT + q0 + wave * 16 + lr) * DHD;
    bf16x8 qf[4];
#pragma unroll
    for (int kk = 0; kk < 4; ++kk) qf[kk] = ld_frag(Qp + kk * 32 + lg * 4);
    f32x4 of[8] = {};
    float m[4] = {-1e30f, -1e30f, -1e30f, -1e30f};
    float l[4] = {};
    const int kv0 = z * (S_TOT / KVSPLIT), kv1 = kv0 + S_TOT / KVSPLIT;
    for (int kb0 = kv0; kb0 < kv1; kb0 += 64) {
        f32x4 sf[4] = {};
        __builtin_amdgcn_s_setprio(1);
#pragma unroll
        for (int n = 0; n < 4; ++n) {
            const bf16_t* Kp = kbuf + ((size_t)h * S_TOT + kb0 + n * 16 + lr) * DHD;
#pragma unroll
            for (int kk = 0; kk < 4; ++kk) {
                bf16x8 kf = ld_frag(Kp + kk * 32 + lg * 4);
                sf[n] = __builtin_amdgcn_mfma_f32_16x16x32_bf16(qf[kk], kf, sf[n], 0, 0, 0);
            }
        }
        __builtin_amdgcn_s_setprio(0);
        float bm[4], alpha[4], rs[4];
#pragma unroll
        for (int r = 0; r < 4; ++r)
            bm[r] = fmaxf(fmaxf(sf[0][r], sf[1][r]), fmaxf(sf[2][r], sf[3][r]));
#pragma unroll
        for (int mask = 1; mask < 16; mask <<= 1)
#pragma unroll
            for (int r = 0; r < 4; ++r) bm[r] = fmaxf(bm[r], __shfl_xor(bm[r], mask));
#pragma unroll
        for (int r = 0; r < 4; ++r) {
            float mn = fmaxf(m[r], bm[r]);
            alpha[r] = __expf(m[r] - mn);
            m[r] = mn;
            rs[r] = 0.f;
        }
#pragma unroll
        for (int n = 0; n < 4; ++n)
#pragma unroll
            for (int r = 0; r < 4; ++r) {
                float p = __expf(sf[n][r] - m[r]);
                rs[r] += p;
                P[wave][lg * 4 + r][n * 16 + lr] = (bf16_t)p;
            }
#pragma unroll
        for (int mask = 1; mask < 16; mask <<= 1)
#pragma unroll
            for (int r = 0; r < 4; ++r) rs[r] += __shfl_xor(rs[r], mask);
#pragma unroll
        for (int r = 0; r < 4; ++r) l[r] = l[r] * alpha[r] + rs[r];
#pragma unroll
        for (int nf = 0; nf < 8; ++nf)
#pragma unroll
            for (int r = 0; r < 4; ++r) of[nf][r] *= alpha[r];
        __syncthreads();
        __builtin_amdgcn_s_setprio(1);
#pragma unroll
        for (int kk2 = 0; kk2 < 2; ++kk2) {
            bf16x8 pf = ld_frag(&P[wave][lr][kk2 * 32 + lg * 4]);
#pragma unroll
            for (int nf = 0; nf < 8; ++nf) {
                const bf16_t* Vp = vt + ((size_t)h * DHD + nf * 16 + lr) * S_TOT + kb0 + kk2 * 32 + lg * 4;
                bf16x8 vf = ld_frag(Vp);
                of[nf] = __builtin_amdgcn_mfma_f32_16x16x32_bf16(pf, vf, of[nf], 0, 0, 0);
            }
        }
        __builtin_amdgcn_s_setprio(0);
        __syncthreads();
    }
    // write partials (un-normalized)
    int hqb = h * 24 + qblk;
    float* po = part_o + ((size_t)z * HQB + hqb) * 8192;
    int rb = wave * 16 + lg * 4;
#pragma unroll
    for (int r = 0; r < 4; ++r)
#pragma unroll
        for (int nf = 0; nf < 8; ++nf)
            po[(rb + r) * 128 + nf * 16 + lr] = of[nf][r];
    if (lr == 0) {
#pragma unroll
        for (int r = 0; r < 4; ++r) {
            size_t mi = (((size_t)z * HQB + hqb) * 64 + rb + r) * 2;
            part_ml[mi]     = m[r];
            part_ml[mi + 1] = l[r];
        }
    }
}

// ---------------------------------------------------------------------------
// KV-split reduce: combine KVSPLIT partials -> bf16 o (S, D). grid 288 x 256.
// ---------------------------------------------------------------------------
__global__ __launch_bounds__(256)
void attn_red(const float* __restrict__ part_o, const float* __restrict__ part_ml,
              bf16_t* __restrict__ o) {
    int hqb = blockIdx.x;
    int h = hqb / 24, q0 = (hqb % 24) * 64;
    __shared__ float wz[KVSPLIT][64];
    __shared__ float invL[64];
    int tid = threadIdx.x;
    if (tid < 64) {
        float mz[KVSPLIT], lz[KVSPLIT];
#pragma unroll
        for (int zz = 0; zz < KVSPLIT; ++zz) {
            size_t mi = (((size_t)zz * HQB + hqb) * 64 + tid) * 2;
            mz[zz] = part_ml[mi];
            lz[zz] = part_ml[mi + 1];
        }
        float M = mz[0];
#pragma unroll
        for (int zz = 1; zz < KVSPLIT; ++zz) M = fmaxf(M, mz[zz]);
        float L = 0.f;
#pragma unroll
        for (int zz = 0; zz < KVSPLIT; ++zz) {
            float w = __expf(mz[zz] - M);
            wz[zz][tid] = w;
            L += w * lz[zz];
        }
        invL[tid] = 1.0f / L;
    }
    __syncthreads();
#pragma unroll
    for (int i = 0; i < 8; ++i) {
        int e4 = tid + 256 * i;
        int row = e4 >> 5, c4 = e4 & 31;
        f32x4 acc = {};
#pragma unroll
        for (int zz = 0; zz < KVSPLIT; ++zz) {
            f32x4 v = *(const f32x4*)&part_o[((size_t)zz * HQB + hqb) * 8192 + row * 128 + c4 * 4];
            float w = wz[zz][row];
            acc[0] += v[0] * w; acc[1] += v[1] * w; acc[2] += v[2] * w; acc[3] += v[3] * w;
        }
        float il = invL[row];
        bf16x4 r;
        r[0] = (bf16_t)(acc[0] * il); r[1] = (bf16_t)(acc[1] * il);
        r[2] = (bf16_t)(acc[2] * il); r[3] = (bf16_t)(acc[3] * il);
        *(bf16x4*)&o[(size_t)(q0 + row) * D_MODEL + h * DHD + c4 * 4] = r;
    }
}

// ---------------------------------------------------------------------------
extern "C" void kernel_launch(void* const* d_in, const int* in_sizes, int n_in,
                              void* d_out, int out_size, void* d_ws, size_t ws_size,
                              hipStream_t stream) {
    const float* hidden  = (const float*)d_in[0];
    const float* encoder = (const float*)d_in[1];
    const float* temb    = (const float*)d_in[2];
    const float* rope    = (const float*)d_in[3];
    const float* adaln_img_w = (const float*)d_in[4];
    const float* adaln_img_b = (const float*)d_in[5];
    const float* adaln_txt_w = (const float*)d_in[6];
    const float* adaln_txt_b = (const float*)d_in[7];
    const float* qkv_img_w = (const float*)d_in[8];
    const float* qkv_img_b = (const float*)d_in[9];
    const float* qkv_txt_w = (const float*)d_in[10];
    const float* qkv_txt_b = (const float*)d_in[11];
    const float* qn_img = (const float*)d_in[12];
    const float* kn_img = (const float*)d_in[13];
    const float* qn_txt = (const float*)d_in[14];
    const float* kn_txt = (const float*)d_in[15];
    const float* out_img_w = (const float*)d_in[16];
    const float* out_img_b = (const float*)d_in[17];
    const float* out_txt_w = (const float*)d_in[18];
    const float* out_txt_b = (const float*)d_in[19];
    const float* mlp_img_w1 = (const float*)d_in[20];
    const float* mlp_img_b1 = (const float*)d_in[21];
    const float* mlp_img_w2 = (const float*)d_in[22];
    const float* mlp_img_b2 = (const float*)d_in[23];
    const float* mlp_txt_w1 = (const float*)d_in[24];
    const float* mlp_txt_b1 = (const float*)d_in[25];
    const float* mlp_txt_w2 = (const float*)d_in[26];
    const float* mlp_txt_b2 = (const float*)d_in[27];
    float* dout = (float*)d_out;
    char* wsb = (char*)d_ws;

    // ws layout (byte offsets), total 70,852,608 B = 67.6 MB.
    float*  emb_i = (float*)(wsb);                    // 9216 f32
    float*  emb_t = (float*)(wsb + 36864);            // 9216 f32
    bf16_t* wreg  = (bf16_t*)(wsb + 73728);           // 37.75 MB region (weights, reused)
    float*  part  = (float*)(wsb + 73728);            // adaln partials overlay
    float*  part_o = (float*)(wsb + 73728);           // attn partial O overlay (exactly 37,748,736 B)
    bf16_t* n1    = (bf16_t*)(wsb + 37822464);        // 1536x1536 bf16 (LN1, later LN2)
    float*  part_ml = (float*)(wsb + 37822464);       // attn (m,l) overlay (n1 dead there)
    bf16_t* qkvb  = (bf16_t*)(wsb + 42541056);        // 1536x4608 bf16
    bf16_t* obuf  = qkvb;                             // alias (qkvb dead after epi/v_tr)
    bf16_t* ffb   = qkvb + 2359296;                   // 1536x6144 bf16
    bf16_t* qb    = (bf16_t*)(wsb + 56696832);        // 12x1536x128 bf16
    bf16_t* kb    = (bf16_t*)(wsb + 61415424);
    bf16_t* vt    = (bf16_t*)(wsb + 66134016);

    // 1. adaLN (K-split + reduce)
    adaln_p<<<dim3(72, 8), 256, 0, stream>>>(temb, adaln_img_w, adaln_txt_w, part);
    adaln_r<<<72, 256, 0, stream>>>(part, adaln_img_b, adaln_txt_b, emb_i, emb_t);
    // 2. LN1 + modulate -> bf16
    ln_mod<<<S_TOT, 256, 0, stream>>>(encoder, hidden, emb_t, emb_i, 0, 1, n1);
    // 3. QKV: convert weights, fused GEMM
    conv_wt<1536, 4608><<<dim3(72, 24, 2), 256, 0, stream>>>(qkv_txt_w, qkv_img_w, wreg);
    gemm2<0, bf16_t><<<dim3(36, 12), 256, 0, stream>>>(
        n1, D_MODEL, wreg, 4608 * 1536, qkv_txt_b, qkv_img_b,
        nullptr, nullptr, 0, nullptr, nullptr, qkvb, 4608, 1536);
    // 4. RMS + RoPE -> bf16 q,k ; V transpose
    qkv_epi<<<dim3(12, 1536), 128, 0, stream>>>(qkvb, rope, qn_img, kn_img, qn_txt, kn_txt, qb, kb);
    v_tr<<<dim3(12, 24), 256, 0, stream>>>(qkvb, vt);
    // 5. attention (KV-split) + reduce -> o bf16
    attn_k<<<dim3(12, 24, KVSPLIT), 256, 0, stream>>>(qb, kb, vt, part_o, part_ml);
    attn_red<<<HQB, 256, 0, stream>>>(part_o, part_ml, obuf);
    // 6. out-proj (fused txt+img) + gate + residual -> d_out
    conv_wt<1536, 1536><<<dim3(24, 24, 2), 256, 0, stream>>>(out_txt_w, out_img_w, wreg);
    gemm3<<<dim3(24, 12), 256, 0, stream>>>(
        obuf, D_MODEL, wreg, 1536 * 1536, out_txt_b, out_img_b,
        encoder, hidden, D_MODEL, emb_t + 2 * D_MODEL, emb_i + 2 * D_MODEL,
        dout, D_MODEL, 1536);
    // 7. LN2 + modulate -> bf16
    ln_mod<<<S_TOT, 256, 0, stream>>>(dout, dout + (size_t)S_TXT * D_MODEL, emb_t, emb_i, 3, 4, n1);
    // 8. MLP up + gelu -> bf16 ff
    conv_wt<1536, 6144><<<dim3(96, 24, 2), 256, 0, stream>>>(mlp_txt_w1, mlp_img_w1, wreg);
    gemm2<1, bf16_t><<<dim3(48, 12), 256, 0, stream>>>(
        n1, D_MODEL, wreg, 6144 * 1536, mlp_txt_b1, mlp_img_b1,
        nullptr, nullptr, 0, nullptr, nullptr, ffb, FF_DIM, 1536);
    // 9. MLP down + gate + residual, in place on d_out
    conv_wt<6144, 1536><<<dim3(24, 96, 2), 256, 0, stream>>>(mlp_txt_w2, mlp_img_w2, wreg);
    gemm3<<<dim3(24, 12), 256, 0, stream>>>(
        ffb, FF_DIM, wreg, 1536 * 6144, mlp_txt_b2, mlp_img_b2,
        dout, dout + (size_t)S_TXT * D_MODEL, D_MODEL,
        emb_t + 5 * D_MODEL, emb_i + 5 * D_MODEL, dout, D_MODEL, 6144);
    (void)in_sizes; (void)n_in; (void)out_size; (void)ws_size;
}

// Round 5
// 394.107 us; speedup vs baseline: 6.8620x; 1.5384x over previous
//
#include <hip/hip_runtime.h>
#include <hip/hip_bf16.h>

typedef __bf16 bf16_t;
typedef __attribute__((ext_vector_type(4))) float f32x4;
typedef __attribute__((ext_vector_type(8))) bf16_t bf16x8;
typedef __attribute__((ext_vector_type(4))) bf16_t bf16x4;
typedef __attribute__((ext_vector_type(2))) bf16_t bf16x2;

#define D_MODEL 1536
#define NH 12
#define DHD 128
#define S_TXT 512
#define S_TOT 1536
#define FF_DIM 6144
#define KVSPLIT 4
#define HQB 288   // 12 heads * 24 q-blocks

// Load an 8-element bf16 MFMA fragment: k-halves at p[0..3] and p[16..19].
__device__ inline bf16x8 ld_frag(const bf16_t* p) {
    bf16x4 a = *(const bf16x4*)p;
    bf16x4 b = *(const bf16x4*)(p + 16);
    bf16x8 r;
    r[0]=a[0]; r[1]=a[1]; r[2]=a[2]; r[3]=a[3];
    r[4]=b[0]; r[5]=b[1]; r[6]=b[2]; r[7]=b[3];
    return r;
}

// async global->LDS, 16 B per lane. LDS dest is wave-uniform base (+lane*16 by HW).
__device__ inline void gload16(const void* g, void* l) {
    __builtin_amdgcn_global_load_lds((const __attribute__((address_space(1))) unsigned int*)g,
                                     (__attribute__((address_space(3))) unsigned int*)l, 16, 0, 0);
}

// ---------------------------------------------------------------------------
// adaLN stage 1: partial dot products, K split 8 ways. grid (72,8) block 256.
// ---------------------------------------------------------------------------
__global__ __launch_bounds__(256)
void adaln_p(const float* __restrict__ temb,
             const float* __restrict__ w_img, const float* __restrict__ w_txt,
             float* __restrict__ part) {
    __shared__ float t[192];
    int tid = threadIdx.x;
    int k0 = blockIdx.y * 192;
    if (tid < 192) {
        float x = temb[k0 + tid];
        t[tid] = x / (1.0f + __expf(-x));
    }
    __syncthreads();
    int n_g = blockIdx.x * 256 + tid;
    bool img = n_g < 9216;
    const float* W = img ? w_img : w_txt;
    int n = img ? n_g : n_g - 9216;
    float acc = 0.f;
    for (int kk = 0; kk < 192; kk += 4) {
        acc += t[kk]     * W[(size_t)(k0 + kk) * 9216 + n];
        acc += t[kk + 1] * W[(size_t)(k0 + kk + 1) * 9216 + n];
        acc += t[kk + 2] * W[(size_t)(k0 + kk + 2) * 9216 + n];
        acc += t[kk + 3] * W[(size_t)(k0 + kk + 3) * 9216 + n];
    }
    part[(size_t)blockIdx.y * 18432 + n_g] = acc;
}

// adaLN stage 2: reduce + bias. grid 72 x 256.
__global__ __launch_bounds__(256)
void adaln_r(const float* __restrict__ part,
             const float* __restrict__ b_img, const float* __restrict__ b_txt,
             float* __restrict__ emb_img, float* __restrict__ emb_txt) {
    int n_g = blockIdx.x * 256 + threadIdx.x;
    float a = 0.f;
#pragma unroll
    for (int kc = 0; kc < 8; ++kc) a += part[(size_t)kc * 18432 + n_g];
    if (n_g < 9216) emb_img[n_g] = a + b_img[n_g];
    else            emb_txt[n_g - 9216] = a + b_txt[n_g - 9216];
}

// ---------------------------------------------------------------------------
// LayerNorm + modulate -> bf16. Rows 0..511 txt, 512..1535 img.
// ---------------------------------------------------------------------------
__global__ __launch_bounds__(256)
void ln_mod(const float* __restrict__ src_txt, const float* __restrict__ src_img,
            const float* __restrict__ emb_t, const float* __restrict__ emb_i,
            int sh_c, int sc_c, bf16_t* __restrict__ out) {
    int row = blockIdx.x;
    bool txt = row < S_TXT;
    const float* src = txt ? src_txt + (size_t)row * D_MODEL
                           : src_img + (size_t)(row - S_TXT) * D_MODEL;
    const float* emb = txt ? emb_t : emb_i;
    int tid = threadIdx.x;
    float2 v[3];
    float s = 0.f, sq = 0.f;
#pragma unroll
    for (int i = 0; i < 3; ++i) {
        v[i] = *(const float2*)(src + tid * 2 + 512 * i);
        s  += v[i].x + v[i].y;
        sq += v[i].x * v[i].x + v[i].y * v[i].y;
    }
#pragma unroll
    for (int off = 32; off > 0; off >>= 1) {
        s  += __shfl_down(s, off);
        sq += __shfl_down(sq, off);
    }
    __shared__ float red[8];
    int wave = tid >> 6, lane = tid & 63;
    if (lane == 0) { red[wave] = s; red[4 + wave] = sq; }
    __syncthreads();
    float ts = red[0] + red[1] + red[2] + red[3];
    float tq = red[4] + red[5] + red[6] + red[7];
    float mean = ts * (1.0f / D_MODEL);
    float var  = tq * (1.0f / D_MODEL) - mean * mean;
    float rstd = rsqrtf(var + 1e-6f);
    bf16_t* op = out + (size_t)row * D_MODEL;
#pragma unroll
    for (int i = 0; i < 3; ++i) {
        int c0 = tid * 2 + 512 * i;
        bf16x2 r;
        r[0] = (bf16_t)((v[i].x - mean) * rstd * (1.0f + emb[sc_c * D_MODEL + c0])     + emb[sh_c * D_MODEL + c0]);
        r[1] = (bf16_t)((v[i].y - mean) * rstd * (1.0f + emb[sc_c * D_MODEL + c0 + 1]) + emb[sh_c * D_MODEL + c0 + 1]);
        *(bf16x2*)(op + c0) = r;
    }
}

// ---------------------------------------------------------------------------
// Weight convert+transpose: W f32 [K][N] -> Wt bf16 [N][K]. grid (N/64,K/64,2).
// ---------------------------------------------------------------------------
template <int K, int N>
__global__ __launch_bounds__(256)
void conv_wt(const float* __restrict__ w_t, const float* __restrict__ w_i,
             bf16_t* __restrict__ dst) {
    __shared__ float tile[64][65];
    const float* src = blockIdx.z ? w_i : w_t;
    bf16_t* d = dst + (size_t)blockIdx.z * N * K;
    int bn = blockIdx.x * 64, bk = blockIdx.y * 64;
    int tid = threadIdx.x;
#pragma unroll
    for (int j = 0; j < 16; ++j) {
        int l = tid + 256 * j;
        int k = l >> 6, n = l & 63;
        tile[k][n] = src[(size_t)(bk + k) * N + bn + n];
    }
    __syncthreads();
#pragma unroll
    for (int j = 0; j < 16; ++j) {
        int l = tid + 256 * j;
        int n = l >> 6, k = l & 63;
        d[(size_t)(bn + n) * K + bk + k] = (bf16_t)tile[k][n];
    }
}

// ---------------------------------------------------------------------------
// bf16 MFMA GEMM: out(MxN) = A(MxK,bf16) @ Wt(NxK,bf16)^T.
// 128x128 tile, BK=64, 4 waves (2x2). 2-phase dbuf pipeline (T3 min),
// LDS XOR-swizzle via pre-swizzled global source (T2/rule21), XCD swizzle (T1).
// EPI: 0=bias  1=bias+gelu(tanh)  2=resid + gate*(bias+acc)
// ---------------------------------------------------------------------------
template <int EPI, typename OutT>
__global__ __launch_bounds__(256)
void gemm2(const bf16_t* __restrict__ A, int lda,
           const bf16_t* __restrict__ Wt, int wimg_off,
           const float* __restrict__ bias_t, const float* __restrict__ bias_i,
           const float* __restrict__ resid_t, const float* __restrict__ resid_i, int ldr,
           const float* __restrict__ gate_t, const float* __restrict__ gate_i,
           OutT* __restrict__ out, int ldo, int K) {
    __shared__ bf16_t As[2][128 * 64];
    __shared__ bf16_t Bs[2][128 * 64];
    const int tid = threadIdx.x;

    const int nbx = gridDim.x;
    const int nwg = nbx * gridDim.y;
    int lb = blockIdx.y * nbx + blockIdx.x;
    if ((nwg & 7) == 0) lb = (lb & 7) * (nwg >> 3) + (lb >> 3);
    const int bm = (lb / nbx) * 128, bn = (lb % nbx) * 128;

    const bool txt = bm < S_TXT;
    const bf16_t* W = txt ? Wt : Wt + wimg_off;
    const float* bias = txt ? bias_t : bias_i;
    const int wave = tid >> 6, lane = tid & 63;
    const int wr = (wave >> 1) * 64, wc = (wave & 1) * 64;
    const int lr = lane & 15, lg = lane >> 4;

    const int srow = wave * 8 + (lane >> 3);
    const int csrc = ((lane & 7) ^ ((lane >> 3) & 7)) * 8;
    const bf16_t* Ab = A + (size_t)(bm + srow) * lda + csrc;
    const bf16_t* Wb = W + (size_t)(bn + srow) * K + csrc;
    const int ldst = (wave * 8) * 64;

    f32x4 acc[4][4] = {};
    const int nt = K >> 6;

    auto stage = [&](int buf, int t) {
#pragma unroll
        for (int j = 0; j < 4; ++j) {
            gload16(Ab + (size_t)j * 32 * lda + t * 64, &As[buf][ldst + j * 2048]);
            gload16(Wb + (size_t)j * 32 * K   + t * 64, &Bs[buf][ldst + j * 2048]);
        }
    };

    stage(0, 0);
    asm volatile("s_waitcnt vmcnt(0)" ::: "memory");
    __builtin_amdgcn_s_barrier();

    int cur = 0;
    for (int t = 0; t < nt; ++t) {
        if (t + 1 < nt) stage(cur ^ 1, t + 1);
#pragma unroll
        for (int kk = 0; kk < 2; ++kk) {
            bf16x8 af[4], bfm[4];
#pragma unroll
            for (int m = 0; m < 4; ++m) {
                int rr = wr + m * 16 + lr;
                af[m] = *(const bf16x8*)&As[cur][rr * 64 + (((kk * 4 + lg) ^ (lr & 7)) * 8)];
            }
#pragma unroll
            for (int n = 0; n < 4; ++n) {
                int rr = wc + n * 16 + lr;
                bfm[n] = *(const bf16x8*)&Bs[cur][rr * 64 + (((kk * 4 + lg) ^ (lr & 7)) * 8)];
            }
#pragma unroll
            for (int m = 0; m < 4; ++m)
#pragma unroll
                for (int n = 0; n < 4; ++n)
                    acc[m][n] = __builtin_amdgcn_mfma_f32_16x16x32_bf16(af[m], bfm[n], acc[m][n], 0, 0, 0);
        }
        asm volatile("s_waitcnt vmcnt(0)" ::: "memory");
        __builtin_amdgcn_s_barrier();
        cur ^= 1;
    }

    const float* gate  = txt ? gate_t : gate_i;
    const float* resid = txt ? resid_t : resid_i;
    const int rbase = txt ? 0 : S_TXT;
#pragma unroll
    for (int m = 0; m < 4; ++m) {
#pragma unroll
        for (int r = 0; r < 4; ++r) {
            int grow = bm + wr + m * 16 + lg * 4 + r;
#pragma unroll
            for (int n = 0; n < 4; ++n) {
                int gcol = bn + wc + n * 16 + lr;
                float v = acc[m][n][r] + bias[gcol];
                if constexpr (EPI == 1) {
                    float x = v;
                    float th = tanhf(0.7978845608028654f * (x + 0.044715f * x * x * x));
                    v = 0.5f * x * (1.0f + th);
                } else if constexpr (EPI == 2) {
                    v = resid[(size_t)(grow - rbase) * ldr + gcol] + gate[gcol] * v;
                }
                out[(size_t)grow * ldo + gcol] = (OutT)v;
            }
        }
    }
}

// ---------------------------------------------------------------------------
// gemm3: same structure, tile 128x64 (TN=64) for N=1536 GEMMs -> 288 blocks.
// EPI=2 only: out = resid + gate*(bias+acc), f32 out. LDS 48 KB -> 3 blk/CU.
// ---------------------------------------------------------------------------
__global__ __launch_bounds__(256)
void gemm3(const bf16_t* __restrict__ A, int lda,
           const bf16_t* __restrict__ Wt, int wimg_off,
           const float* __restrict__ bias_t, const float* __restrict__ bias_i,
           const float* __restrict__ resid_t, const float* __restrict__ resid_i, int ldr,
           const float* __restrict__ gate_t, const float* __restrict__ gate_i,
           float* __restrict__ out, int ldo, int K) {
    __shared__ bf16_t As[2][128 * 64];
    __shared__ bf16_t Bs[2][64 * 64];
    const int tid = threadIdx.x;

    const int nbx = gridDim.x;                 // 24 N-tiles
    const int nwg = nbx * gridDim.y;
    int lb = blockIdx.y * nbx + blockIdx.x;
    if ((nwg & 7) == 0) lb = (lb & 7) * (nwg >> 3) + (lb >> 3);
    const int bm = (lb / nbx) * 128, bn = (lb % nbx) * 64;

    const bool txt = bm < S_TXT;
    const bf16_t* W = txt ? Wt : Wt + wimg_off;
    const float* bias = txt ? bias_t : bias_i;
    const int wave = tid >> 6, lane = tid & 63;
    const int wr = (wave >> 1) * 64, wc = (wave & 1) * 32;
    const int lr = lane & 15, lg = lane >> 4;

    const int srow = wave * 8 + (lane >> 3);
    const int csrc = ((lane & 7) ^ ((lane >> 3) & 7)) * 8;
    const bf16_t* Ab = A + (size_t)(bm + srow) * lda + csrc;
    const bf16_t* Wb = W + (size_t)(bn + srow) * K + csrc;
    const int ldst = (wave * 8) * 64;

    f32x4 acc[4][2] = {};
    const int nt = K >> 6;

    auto stage = [&](int buf, int t) {
#pragma unroll
        for (int j = 0; j < 4; ++j)
            gload16(Ab + (size_t)j * 32 * lda + t * 64, &As[buf][ldst + j * 2048]);
#pragma unroll
        for (int j = 0; j < 2; ++j)
            gload16(Wb + (size_t)j * 32 * K + t * 64, &Bs[buf][ldst + j * 2048]);
    };

    stage(0, 0);
    asm volatile("s_waitcnt vmcnt(0)" ::: "memory");
    __builtin_amdgcn_s_barrier();

    int cur = 0;
    for (int t = 0; t < nt; ++t) {
        if (t + 1 < nt) stage(cur ^ 1, t + 1);
#pragma unroll
        for (int kk = 0; kk < 2; ++kk) {
            bf16x8 af[4], bfm[2];
#pragma unroll
            for (int m = 0; m < 4; ++m) {
                int rr = wr + m * 16 + lr;
                af[m] = *(const bf16x8*)&As[cur][rr * 64 + (((kk * 4 + lg) ^ (lr & 7)) * 8)];
            }
#pragma unroll
            for (int n = 0; n < 2; ++n) {
                int rr = wc + n * 16 + lr;
                bfm[n] = *(const bf16x8*)&Bs[cur][rr * 64 + (((kk * 4 + lg) ^ (lr & 7)) * 8)];
            }
#pragma unroll
            for (int m = 0; m < 4; ++m)
#pragma unroll
                for (int n = 0; n < 2; ++n)
                    acc[m][n] = __builtin_amdgcn_mfma_f32_16x16x32_bf16(af[m], bfm[n], acc[m][n], 0, 0, 0);
        }
        asm volatile("s_waitcnt vmcnt(0)" ::: "memory");
        __builtin_amdgcn_s_barrier();
        cur ^= 1;
    }

    const float* gate  = txt ? gate_t : gate_i;
    const float* resid = txt ? resid_t : resid_i;
    const int rbase = txt ? 0 : S_TXT;
#pragma unroll
    for (int m = 0; m < 4; ++m) {
#pragma unroll
        for (int r = 0; r < 4; ++r) {
            int grow = bm + wr + m * 16 + lg * 4 + r;
#pragma unroll
            for (int n = 0; n < 2; ++n) {
                int gcol = bn + wc + n * 16 + lr;
                float v = acc[m][n][r] + bias[gcol];
                v = resid[(size_t)(grow - rbase) * ldr + gcol] + gate[gcol] * v;
                out[(size_t)grow * ldo + gcol] = v;
            }
        }
    }
}

// ---------------------------------------------------------------------------
// QKV epilogue: RMS-norm(q,k) + RoPE + fold 1/sqrt(DH) into q; bf16 in/out.
// ---------------------------------------------------------------------------
__global__ __launch_bounds__(128)
void qkv_epi(const bf16_t* __restrict__ qkv, const float* __restrict__ rope,
             const float* __restrict__ qn_i, const float* __restrict__ kn_i,
             const float* __restrict__ qn_t, const float* __restrict__ kn_t,
             bf16_t* __restrict__ qb, bf16_t* __restrict__ kb) {
    int h = blockIdx.x, s = blockIdx.y, dh = threadIdx.x;
    bool txt = s < S_TXT;
    const float* qn = txt ? qn_t : qn_i;
    const float* kn = txt ? kn_t : kn_i;
    const bf16_t* base = qkv + (size_t)s * 4608 + h * DHD + dh;
    float q = (float)base[0];
    float k = (float)base[D_MODEL];
    float qs = q * q, ks = k * k;
#pragma unroll
    for (int off = 32; off > 0; off >>= 1) {
        qs += __shfl_down(qs, off);
        ks += __shfl_down(ks, off);
    }
    __shared__ float red[4];
    if ((threadIdx.x & 63) == 0) {
        red[(threadIdx.x >> 6) * 2]     = qs;
        red[(threadIdx.x >> 6) * 2 + 1] = ks;
    }
    __syncthreads();
    float qr = rsqrtf((red[0] + red[2]) * (1.0f / DHD) + 1e-6f);
    float kr = rsqrtf((red[1] + red[3]) * (1.0f / DHD) + 1e-6f);
    q = q * qr * qn[dh];
    k = k * kr * kn[dh];
    int i = dh & 1, d = dh >> 1;
    const float* rp = rope + ((size_t)s * 64 + d) * 4 + i * 2;
    float r0 = rp[0], r1 = rp[1];
    float qo = __shfl_xor(q, 1), ko = __shfl_xor(k, 1);
    float q0 = i ? qo : q, q1 = i ? q : qo;
    float k0 = i ? ko : k, k1 = i ? k : ko;
    float qq = r0 * q0 + r1 * q1;
    float kk = r0 * k0 + r1 * k1;
    size_t idx = ((size_t)h * S_TOT + s) * DHD + dh;
    qb[idx] = (bf16_t)(qq * 0.08838834764831845f);  // 1/sqrt(128)
    kb[idx] = (bf16_t)kk;
}

// ---------------------------------------------------------------------------
// V transpose: per-head vT[DH][S] bf16. grid (12, 24), block 256.
// ---------------------------------------------------------------------------
__global__ __launch_bounds__(256)
void v_tr(const bf16_t* __restrict__ qkv, bf16_t* __restrict__ vt) {
    __shared__ bf16_t tile[64][130];
    int h = blockIdx.x, sb = blockIdx.y * 64;
    int tid = threadIdx.x;
#pragma unroll
    for (int j = 0; j < 32; ++j) {
        int linear = tid + 256 * j;
        int sl = linear >> 7, dh = linear & 127;
        tile[sl][dh] = qkv[(size_t)(sb + sl) * 4608 + 2 * D_MODEL + h * DHD + dh];
    }
    __syncthreads();
#pragma unroll
    for (int j = 0; j < 32; ++j) {
        int linear = tid + 256 * j;
        int dh = linear >> 6, sl = linear & 63;
        vt[((size_t)h * DHD + dh) * S_TOT + sb + sl] = tile[sl][dh];
    }
}

// ---------------------------------------------------------------------------
// Flash attention, KV-split, LDS-staged K/V (gemm2-style swizzled staging):
// grid (12, 24, KVSPLIT), 4 waves x 16 q-rows. K-tile [64][128] and V-tile
// [128][64] staged via global_load_lds with XOR-pre-swizzled source; frag
// reads un-XOR to true k-chunks. P is wave-private swizzled LDS (no barrier).
// One vmcnt(0)+s_barrier per KV tile; 2-phase double buffer.
// ---------------------------------------------------------------------------
__global__ __launch_bounds__(256)
void attn_k(const bf16_t* __restrict__ qbuf, const bf16_t* __restrict__ kbuf,
            const bf16_t* __restrict__ vt,
            float* __restrict__ part_o, float* __restrict__ part_ml) {
    __shared__ bf16_t Ks[2][64 * 128];
    __shared__ bf16_t Vs[2][128 * 64];
    __shared__ bf16_t P[4][16 * 64];
    int h = blockIdx.x, qblk = blockIdx.y, z = blockIdx.z;
    int q0 = qblk * 64;
    int tid = threadIdx.x, wave = tid >> 6, lane = tid & 63;
    int lr = lane & 15, lg = lane >> 4;

    // Q fragments: true contiguous chunks (same chunk scheme as K-frag reads)
    const bf16_t* Qp = qbuf + ((size_t)h * S_TOT + q0 + wave * 16 + lr) * DHD;
    bf16x8 qf[4];
#pragma unroll
    for (int kk = 0; kk < 4; ++kk) qf[kk] = *(const bf16x8*)(Qp + (kk * 4 + lg) * 8);

    // K staging: row sKr (+16/round), chunk cK (of 16); src col pre-XOR'd
    const int sKr = wave * 4 + (lane >> 4);
    const int cK = lane & 15;
    const bf16_t* Kb = kbuf + ((size_t)h * S_TOT + sKr) * DHD + ((cK ^ (sKr & 7)) * 8);
    const int ldsK = sKr * 128 - (lane >> 4) * 128 + 0;  // wave*4*128 (wave-uniform)
    // V staging: row sVr (+32/round), chunk cV (of 8); src col pre-XOR'd
    const int sVr = wave * 8 + (lane >> 3);
    const int cV = lane & 7;
    const bf16_t* Vb = vt + ((size_t)h * DHD + sVr) * S_TOT + ((cV ^ (sVr & 7)) * 8);
    const int ldsV = (wave * 8) * 64;

    auto stage = [&](int buf, int kb0) {
#pragma unroll
        for (int j = 0; j < 4; ++j) {
            gload16(Kb + (size_t)(kb0 + j * 16) * DHD, &Ks[buf][(wave * 4) * 128 + j * 2048]);
            gload16(Vb + kb0 + (size_t)j * 32 * S_TOT, &Vs[buf][ldsV + j * 2048]);
        }
    };

    f32x4 of[8] = {};
    float m[4] = {-1e30f, -1e30f, -1e30f, -1e30f};
    float l[4] = {};
    const int kv0 = z * (S_TOT / KVSPLIT);
    const int nt = (S_TOT / KVSPLIT) / 64;

    stage(0, kv0);
    asm volatile("s_waitcnt vmcnt(0)" ::: "memory");
    __builtin_amdgcn_s_barrier();

    int cur = 0;
    for (int t = 0; t < nt; ++t) {
        if (t + 1 < nt) stage(cur ^ 1, kv0 + (t + 1) * 64);
        // ---- QK^T from LDS (reads un-XOR to true chunks) ----
        f32x4 sf[4] = {};
        __builtin_amdgcn_s_setprio(1);
#pragma unroll
        for (int n = 0; n < 4; ++n) {
#pragma unroll
            for (int kk = 0; kk < 4; ++kk) {
                bf16x8 kf = *(const bf16x8*)&Ks[cur][(n * 16 + lr) * 128 + (((kk * 4 + lg) ^ (lr & 7)) * 8)];
                sf[n] = __builtin_amdgcn_mfma_f32_16x16x32_bf16(qf[kk], kf, sf[n], 0, 0, 0);
            }
        }
        __builtin_amdgcn_s_setprio(0);
        // ---- online softmax ----
        float bm[4], alpha[4], rs[4];
#pragma unroll
        for (int r = 0; r < 4; ++r)
            bm[r] = fmaxf(fmaxf(sf[0][r], sf[1][r]), fmaxf(sf[2][r], sf[3][r]));
#pragma unroll
        for (int mask = 1; mask < 16; mask <<= 1)
#pragma unroll
            for (int r = 0; r < 4; ++r) bm[r] = fmaxf(bm[r], __shfl_xor(bm[r], mask));
#pragma unroll
        for (int r = 0; r < 4; ++r) {
            float mn = fmaxf(m[r], bm[r]);
            alpha[r] = __expf(m[r] - mn);
            m[r] = mn;
            rs[r] = 0.f;
        }
        // P write: row=lg*4+r (q), col=n*16+lr (kv); swizzled chunk layout
#pragma unroll
        for (int n = 0; n < 4; ++n)
#pragma unroll
            for (int r = 0; r < 4; ++r) {
                float p = __expf(sf[n][r] - m[r]);
                rs[r] += p;
                int row = lg * 4 + r, col = n * 16 + lr;
                P[wave][row * 64 + ((((col >> 3) ^ (row & 7)) << 3) | (col & 7))] = (bf16_t)p;
            }
#pragma unroll
        for (int mask = 1; mask < 16; mask <<= 1)
#pragma unroll
            for (int r = 0; r < 4; ++r) rs[r] += __shfl_xor(rs[r], mask);
#pragma unroll
        for (int r = 0; r < 4; ++r) l[r] = l[r] * alpha[r] + rs[r];
#pragma unroll
        for (int nf = 0; nf < 8; ++nf)
#pragma unroll
            for (int r = 0; r < 4; ++r) of[nf][r] *= alpha[r];
        // ---- PV: P wave-private (compiler-ordered ds ops, no barrier) ----
        __builtin_amdgcn_s_setprio(1);
#pragma unroll
        for (int kk2 = 0; kk2 < 2; ++kk2) {
            bf16x8 pf = *(const bf16x8*)&P[wave][lr * 64 + (((kk2 * 4 + lg) ^ (lr & 7)) * 8)];
#pragma unroll
            for (int nf = 0; nf < 8; ++nf) {
                bf16x8 vf = *(const bf16x8*)&Vs[cur][(nf * 16 + lr) * 64 + (((kk2 * 4 + lg) ^ (lr & 7)) * 8)];
                of[nf] = __builtin_amdgcn_mfma_f32_16x16x32_bf16(pf, vf, of[nf], 0, 0, 0);
            }
        }
        __builtin_amdgcn_s_setprio(0);
        asm volatile("s_waitcnt vmcnt(0)" ::: "memory");  // next tile staged
        __builtin_amdgcn_s_barrier();                     // all waves done with cur
        cur ^= 1;
    }
    // write partials (un-normalized)
    int hqb = h * 24 + qblk;
    float* po = part_o + ((size_t)z * HQB + hqb) * 8192;
    int rb = wave * 16 + lg * 4;
#pragma unroll
    for (int r = 0; r < 4; ++r)
#pragma unroll
        for (int nf = 0; nf < 8; ++nf)
            po[(rb + r) * 128 + nf * 16 + lr] = of[nf][r];
    if (lr == 0) {
#pragma unroll
        for (int r = 0; r < 4; ++r) {
            size_t mi = (((size_t)z * HQB + hqb) * 64 + rb + r) * 2;
            part_ml[mi]     = m[r];
            part_ml[mi + 1] = l[r];
        }
    }
}

// ---------------------------------------------------------------------------
// KV-split reduce: combine KVSPLIT partials -> bf16 o (S, D). grid 288 x 256.
// ---------------------------------------------------------------------------
__global__ __launch_bounds__(256)
void attn_red(const float* __restrict__ part_o, const float* __restrict__ part_ml,
              bf16_t* __restrict__ o) {
    int hqb = blockIdx.x;
    int h = hqb / 24, q0 = (hqb % 24) * 64;
    __shared__ float wz[KVSPLIT][64];
    __shared__ float invL[64];
    int tid = threadIdx.x;
    if (tid < 64) {
        float mz[KVSPLIT], lz[KVSPLIT];
#pragma unroll
        for (int zz = 0; zz < KVSPLIT; ++zz) {
            size_t mi = (((size_t)zz * HQB + hqb) * 64 + tid) * 2;
            mz[zz] = part_ml[mi];
            lz[zz] = part_ml[mi + 1];
        }
        float M = mz[0];
#pragma unroll
        for (int zz = 1; zz < KVSPLIT; ++zz) M = fmaxf(M, mz[zz]);
        float L = 0.f;
#pragma unroll
        for (int zz = 0; zz < KVSPLIT; ++zz) {
            float w = __expf(mz[zz] - M);
            wz[zz][tid] = w;
            L += w * lz[zz];
        }
        invL[tid] = 1.0f / L;
    }
    __syncthreads();
#pragma unroll
    for (int i = 0; i < 8; ++i) {
        int e4 = tid + 256 * i;
        int row = e4 >> 5, c4 = e4 & 31;
        f32x4 acc = {};
#pragma unroll
        for (int zz = 0; zz < KVSPLIT; ++zz) {
            f32x4 v = *(const f32x4*)&part_o[((size_t)zz * HQB + hqb) * 8192 + row * 128 + c4 * 4];
            float w = wz[zz][row];
            acc[0] += v[0] * w; acc[1] += v[1] * w; acc[2] += v[2] * w; acc[3] += v[3] * w;
        }
        float il = invL[row];
        bf16x4 r;
        r[0] = (bf16_t)(acc[0] * il); r[1] = (bf16_t)(acc[1] * il);
        r[2] = (bf16_t)(acc[2] * il); r[3] = (bf16_t)(acc[3] * il);
        *(bf16x4*)&o[(size_t)(q0 + row) * D_MODEL + h * DHD + c4 * 4] = r;
    }
}

// ---------------------------------------------------------------------------
extern "C" void kernel_launch(void* const* d_in, const int* in_sizes, int n_in,
                              void* d_out, int out_size, void* d_ws, size_t ws_size,
                              hipStream_t stream) {
    const float* hidden  = (const float*)d_in[0];
    const float* encoder = (const float*)d_in[1];
    const float* temb    = (const float*)d_in[2];
    const float* rope    = (const float*)d_in[3];
    const float* adaln_img_w = (const float*)d_in[4];
    const float* adaln_img_b = (const float*)d_in[5];
    const float* adaln_txt_w = (const float*)d_in[6];
    const float* adaln_txt_b = (const float*)d_in[7];
    const float* qkv_img_w = (const float*)d_in[8];
    const float* qkv_img_b = (const float*)d_in[9];
    const float* qkv_txt_w = (const float*)d_in[10];
    const float* qkv_txt_b = (const float*)d_in[11];
    const float* qn_img = (const float*)d_in[12];
    const float* kn_img = (const float*)d_in[13];
    const float* qn_txt = (const float*)d_in[14];
    const float* kn_txt = (const float*)d_in[15];
    const float* out_img_w = (const float*)d_in[16];
    const float* out_img_b = (const float*)d_in[17];
    const float* out_txt_w = (const float*)d_in[18];
    const float* out_txt_b = (const float*)d_in[19];
    const float* mlp_img_w1 = (const float*)d_in[20];
    const float* mlp_img_b1 = (const float*)d_in[21];
    const float* mlp_img_w2 = (const float*)d_in[22];
    const float* mlp_img_b2 = (const float*)d_in[23];
    const float* mlp_txt_w1 = (const float*)d_in[24];
    const float* mlp_txt_b1 = (const float*)d_in[25];
    const float* mlp_txt_w2 = (const float*)d_in[26];
    const float* mlp_txt_b2 = (const float*)d_in[27];
    float* dout = (float*)d_out;
    char* wsb = (char*)d_ws;

    // ws layout (byte offsets), total 70,852,608 B = 67.6 MB.
    float*  emb_i = (float*)(wsb);                    // 9216 f32
    float*  emb_t = (float*)(wsb + 36864);            // 9216 f32
    bf16_t* wreg  = (bf16_t*)(wsb + 73728);           // 37.75 MB region (weights, reused)
    float*  part  = (float*)(wsb + 73728);            // adaln partials overlay
    float*  part_o = (float*)(wsb + 73728);           // attn partial O overlay (37,748,736 B)
    bf16_t* n1    = (bf16_t*)(wsb + 37822464);        // 1536x1536 bf16 (LN1, later LN2)
    float*  part_ml = (float*)(wsb + 37822464);       // attn (m,l) overlay (n1 dead there)
    bf16_t* qkvb  = (bf16_t*)(wsb + 42541056);        // 1536x4608 bf16
    bf16_t* obuf  = qkvb;                             // alias (qkvb dead after epi/v_tr)
    bf16_t* ffb   = qkvb + 2359296;                   // 1536x6144 bf16
    bf16_t* qb    = (bf16_t*)(wsb + 56696832);        // 12x1536x128 bf16
    bf16_t* kb    = (bf16_t*)(wsb + 61415424);
    bf16_t* vt    = (bf16_t*)(wsb + 66134016);

    // 1. adaLN (K-split + reduce)
    adaln_p<<<dim3(72, 8), 256, 0, stream>>>(temb, adaln_img_w, adaln_txt_w, part);
    adaln_r<<<72, 256, 0, stream>>>(part, adaln_img_b, adaln_txt_b, emb_i, emb_t);
    // 2. LN1 + modulate -> bf16
    ln_mod<<<S_TOT, 256, 0, stream>>>(encoder, hidden, emb_t, emb_i, 0, 1, n1);
    // 3. QKV: convert weights, fused GEMM
    conv_wt<1536, 4608><<<dim3(72, 24, 2), 256, 0, stream>>>(qkv_txt_w, qkv_img_w, wreg);
    gemm2<0, bf16_t><<<dim3(36, 12), 256, 0, stream>>>(
        n1, D_MODEL, wreg, 4608 * 1536, qkv_txt_b, qkv_img_b,
        nullptr, nullptr, 0, nullptr, nullptr, qkvb, 4608, 1536);
    // 4. RMS + RoPE -> bf16 q,k ; V transpose
    qkv_epi<<<dim3(12, 1536), 128, 0, stream>>>(qkvb, rope, qn_img, kn_img, qn_txt, kn_txt, qb, kb);
    v_tr<<<dim3(12, 24), 256, 0, stream>>>(qkvb, vt);
    // 5. attention (KV-split, LDS-staged) + reduce -> o bf16
    attn_k<<<dim3(12, 24, KVSPLIT), 256, 0, stream>>>(qb, kb, vt, part_o, part_ml);
    attn_red<<<HQB, 256, 0, stream>>>(part_o, part_ml, obuf);
    // 6. out-proj (fused txt+img) + gate + residual -> d_out
    conv_wt<1536, 1536><<<dim3(24, 24, 2), 256, 0, stream>>>(out_txt_w, out_img_w, wreg);
    gemm3<<<dim3(24, 12), 256, 0, stream>>>(
        obuf, D_MODEL, wreg, 1536 * 1536, out_txt_b, out_img_b,
        encoder, hidden, D_MODEL, emb_t + 2 * D_MODEL, emb_i + 2 * D_MODEL,
        dout, D_MODEL, 1536);
    // 7. LN2 + modulate -> bf16
    ln_mod<<<S_TOT, 256, 0, stream>>>(dout, dout + (size_t)S_TXT * D_MODEL, emb_t, emb_i, 3, 4, n1);
    // 8. MLP up + gelu -> bf16 ff
    conv_wt<1536, 6144><<<dim3(96, 24, 2), 256, 0, stream>>>(mlp_txt_w1, mlp_img_w1, wreg);
    gemm2<1, bf16_t><<<dim3(48, 12), 256, 0, stream>>>(
        n1, D_MODEL, wreg, 6144 * 1536, mlp_txt_b1, mlp_img_b1,
        nullptr, nullptr, 0, nullptr, nullptr, ffb, FF_DIM, 1536);
    // 9. MLP down + gate + residual, in place on d_out
    conv_wt<6144, 1536><<<dim3(24, 96, 2), 256, 0, stream>>>(mlp_txt_w2, mlp_img_w2, wreg);
    gemm3<<<dim3(24, 12), 256, 0, stream>>>(
        ffb, FF_DIM, wreg, 1536 * 6144, mlp_txt_b2, mlp_img_b2,
        dout, dout + (size_t)S_TXT * D_MODEL, D_MODEL,
        emb_t + 5 * D_MODEL, emb_i + 5 * D_MODEL, dout, D_MODEL, 6144);
    (void)in_sizes; (void)n_in; (void)out_size; (void)ws_size;
}